// Round 1
// baseline (4973.650 us; speedup 1.0000x reference)
//
#include <hip/hip_runtime.h>
#include <hip/hip_bf16.h>

#define H64 64

// ---------------------------------------------------------------------------
// scatter: m[dst] += h[src] * orient   (one wave per adjacency entry)
// ---------------------------------------------------------------------------
__global__ __launch_bounds__(256) void scatter_kernel(
    const float* __restrict__ h, const int* __restrict__ idx,
    const float* __restrict__ orient, float* __restrict__ m, int nadj)
{
    long long gid = (long long)blockIdx.x * 256 + threadIdx.x;
    int e = (int)(gid >> 6);
    if (e >= nadj) return;
    int f = (int)(gid & 63);
    int src = idx[e];
    int dst = idx[nadj + e];
    float v = h[(size_t)src * H64 + f] * orient[e];
    atomicAdd(&m[(size_t)dst * H64 + f], v);
}

// ---------------------------------------------------------------------------
// fused h_out = tanh(hin @ Ws^T + mup @ Wu^T + mdn @ Wd^T)
// 256 threads: 4 rows x 64 cols, loop over 8 row-groups (32 rows/block)
// ---------------------------------------------------------------------------
#define TILE_ROWS 32
__global__ __launch_bounds__(256) void gemm_tanh_kernel(
    const float* __restrict__ hin, const float* __restrict__ mup,
    const float* __restrict__ mdn,
    const float* __restrict__ Ws, const float* __restrict__ Wu,
    const float* __restrict__ Wd,
    float* __restrict__ hout, int E)
{
    __shared__ float Wt[3][64][65];   // [mat][k][j], padded (+1) vs bank conflicts
    __shared__ float rows[3][4][64];  // [mat][r][k]

    int tid = threadIdx.x;
    for (int i = tid; i < 4096; i += 256) {
        int j = i >> 6, k = i & 63;
        Wt[0][k][j] = Ws[i];
        Wt[1][k][j] = Wu[i];
        Wt[2][k][j] = Wd[i];
    }
    __syncthreads();

    int r = tid >> 6;    // 0..3
    int j = tid & 63;    // 0..63
    int base = blockIdx.x * TILE_ROWS;

    for (int g = 0; g < TILE_ROWS / 4; ++g) {
        int i0 = base + g * 4;
        __syncthreads();  // protect rows[] from previous group's readers
        for (int idx2 = tid; idx2 < 768; idx2 += 256) {
            int m  = idx2 >> 8;        // 0..2
            int rr = (idx2 >> 6) & 3;  // 0..3
            int f  = idx2 & 63;
            int row = i0 + rr;
            const float* src = (m == 0) ? hin : ((m == 1) ? mup : mdn);
            rows[m][rr][f] = (row < E) ? src[(size_t)row * H64 + f] : 0.f;
        }
        __syncthreads();

        int row = i0 + r;
        if (row < E) {
            float acc = 0.f;
            #pragma unroll
            for (int k = 0; k < 64; ++k) {
                acc += rows[0][r][k] * Wt[0][k][j];
                acc += rows[1][r][k] * Wt[1][k][j];
                acc += rows[2][r][k] * Wt[2][k][j];
            }
            // tanh(x) = 1 - 2/(exp(2x)+1)  (NaN-free at +/-inf)
            float e = __expf(2.f * acc);
            hout[(size_t)row * H64 + j] = 1.f - 2.f / (e + 1.f);
        }
    }
}

// ---------------------------------------------------------------------------
// pooled[batch[i]] += |h[i]|  (batch sorted -> register-accumulate per wave)
// one wave handles ROWS_PER_WAVE consecutive rows; lane = feature
// ---------------------------------------------------------------------------
#define ROWS_PER_WAVE 64
__global__ __launch_bounds__(256) void pool_kernel(
    const float* __restrict__ h, const int* __restrict__ batch,
    float* __restrict__ pooled, int E)
{
    int wave = (int)((blockIdx.x * 256 + threadIdx.x) >> 6);
    int j = threadIdx.x & 63;
    int row0 = wave * ROWS_PER_WAVE;
    if (row0 >= E) return;
    int row1 = min(row0 + ROWS_PER_WAVE, E);

    int cur = batch[row0];
    float acc = 0.f;
    for (int i = row0; i < row1; ++i) {
        int b = batch[i];
        if (b != cur) {
            atomicAdd(&pooled[(size_t)cur * H64 + j], acc);
            acc = 0.f;
            cur = b;
        }
        acc += fabsf(h[(size_t)i * H64 + j]);
    }
    atomicAdd(&pooled[(size_t)cur * H64 + j], acc);
}

// ---------------------------------------------------------------------------
// head: z = relu(pooled @ lin1^T + b1); out = z @ lin2^T + b2
// one block (64 threads) per graph
// ---------------------------------------------------------------------------
__global__ __launch_bounds__(64) void head_kernel(
    const float* __restrict__ pooled,
    const float* __restrict__ lin1_w, const float* __restrict__ lin1_b,
    const float* __restrict__ lin2_w, const float* __restrict__ lin2_b,
    float* __restrict__ out, int C)
{
    __shared__ float p[64];
    __shared__ float z[64];
    int b = blockIdx.x;
    int t = threadIdx.x;

    p[t] = pooled[(size_t)b * H64 + t];
    __syncthreads();

    float acc = lin1_b[t];
    #pragma unroll
    for (int k = 0; k < 64; ++k) acc += p[k] * lin1_w[t * 64 + k];
    z[t] = fmaxf(acc, 0.f);
    __syncthreads();

    if (t < C) {
        float o = lin2_b[t];
        #pragma unroll
        for (int k = 0; k < 64; ++k) o += z[k] * lin2_w[t * 64 + k];
        out[(size_t)b * C + t] = o;
    }
}

// ---------------------------------------------------------------------------
extern "C" void kernel_launch(void* const* d_in, const int* in_sizes, int n_in,
                              void* d_out, int out_size, void* d_ws, size_t ws_size,
                              hipStream_t stream)
{
    const float* x          = (const float*)d_in[0];
    const int*   up_index   = (const int*)  d_in[1];
    const float* up_orient  = (const float*)d_in[2];
    const int*   down_index = (const int*)  d_in[3];
    const float* down_orient= (const float*)d_in[4];
    const int*   batch      = (const int*)  d_in[5];
    const float* W_up       = (const float*)d_in[6];
    const float* W_down     = (const float*)d_in[7];
    const float* W_self     = (const float*)d_in[8];
    const float* lin1_w     = (const float*)d_in[9];
    const float* lin1_b     = (const float*)d_in[10];
    const float* lin2_w     = (const float*)d_in[11];
    const float* lin2_b     = (const float*)d_in[12];
    float* out = (float*)d_out;

    const int E    = in_sizes[0] / H64;
    const int NADJ = in_sizes[1] / 2;
    const int C    = in_sizes[11] / H64;
    const int B    = out_size / C;
    const int L    = in_sizes[6] / (H64 * H64);

    float* hbuf   = (float*)d_ws;                 // E*64
    float* mup    = hbuf + (size_t)E * H64;       // E*64
    float* mdn    = mup  + (size_t)E * H64;       // E*64
    float* pooled = mdn  + (size_t)E * H64;       // B*64

    const int scatter_blocks = (int)(((long long)NADJ * 64 + 255) / 256);
    const int gemm_blocks    = (E + TILE_ROWS - 1) / TILE_ROWS;
    const int pool_waves     = (E + ROWS_PER_WAVE - 1) / ROWS_PER_WAVE;
    const int pool_blocks    = (pool_waves + 3) / 4;

    for (int l = 0; l < L; ++l) {
        const float* hin = (l == 0) ? x : hbuf;
        // mup & mdn are contiguous: one memset
        hipMemsetAsync(mup, 0, (size_t)2 * E * H64 * sizeof(float), stream);
        scatter_kernel<<<scatter_blocks, 256, 0, stream>>>(hin, up_index, up_orient, mup, NADJ);
        scatter_kernel<<<scatter_blocks, 256, 0, stream>>>(hin, down_index, down_orient, mdn, NADJ);
        gemm_tanh_kernel<<<gemm_blocks, 256, 0, stream>>>(
            hin, mup, mdn,
            W_self + (size_t)l * 4096, W_up + (size_t)l * 4096, W_down + (size_t)l * 4096,
            hbuf, E);
    }

    hipMemsetAsync(pooled, 0, (size_t)B * H64 * sizeof(float), stream);
    pool_kernel<<<pool_blocks, 256, 0, stream>>>(hbuf, batch, pooled, E);
    head_kernel<<<B, 64, 0, stream>>>(pooled, lin1_w, lin1_b, lin2_w, lin2_b, out, C);
}

// Round 2
// 2108.093 us; speedup vs baseline: 2.3593x; 2.3593x over previous
//
#include <hip/hip_runtime.h>
#include <hip/hip_bf16.h>

#define H64 64
typedef float float4a __attribute__((ext_vector_type(4)));

// ---------------------------------------------------------------------------
// CSR build: histogram of dst -> exclusive scan -> reorder (src|sign packed)
// ---------------------------------------------------------------------------
__global__ __launch_bounds__(256) void hist_kernel(
    const int* __restrict__ idx_dst, int* __restrict__ deg, int nadj)
{
    int e = blockIdx.x * 256 + threadIdx.x;
    if (e < nadj) atomicAdd(&deg[idx_dst[e]], 1);
}

#define SCAN_B 256
#define SCAN_TILE 1024

__global__ __launch_bounds__(256) void scan_partial(
    const int* __restrict__ deg, int* __restrict__ bsums, int n)
{
    __shared__ int s[SCAN_B];
    int t = threadIdx.x;
    int i0 = blockIdx.x * SCAN_TILE + t * 4;
    int sum = 0;
    if (i0 + 3 < n) {
        int4 v = *(const int4*)(deg + i0);
        sum = v.x + v.y + v.z + v.w;
    } else {
        for (int k = 0; k < 4; ++k) if (i0 + k < n) sum += deg[i0 + k];
    }
    s[t] = sum; __syncthreads();
    for (int off = 128; off > 0; off >>= 1) {
        if (t < off) s[t] += s[t + off];
        __syncthreads();
    }
    if (t == 0) bsums[blockIdx.x] = s[0];
}

__global__ void scan_bsums_k(int* bsums, int nblk)
{
    if (threadIdx.x == 0 && blockIdx.x == 0) {
        int run = 0;
        for (int i = 0; i < nblk; ++i) { int v = bsums[i]; bsums[i] = run; run += v; }
    }
}

__global__ __launch_bounds__(256) void scan_final(
    const int* __restrict__ deg, const int* __restrict__ bsums,
    int* __restrict__ outx, int n)
{
    __shared__ int s[SCAN_B];
    int t = threadIdx.x;
    int i0 = blockIdx.x * SCAN_TILE + t * 4;
    int v0 = 0, v1 = 0, v2 = 0, v3 = 0;
    if (i0 + 3 < n) {
        int4 v = *(const int4*)(deg + i0);
        v0 = v.x; v1 = v.y; v2 = v.z; v3 = v.w;
    } else {
        if (i0     < n) v0 = deg[i0];
        if (i0 + 1 < n) v1 = deg[i0 + 1];
        if (i0 + 2 < n) v2 = deg[i0 + 2];
        if (i0 + 3 < n) v3 = deg[i0 + 3];
    }
    int tsum = v0 + v1 + v2 + v3;
    s[t] = tsum; __syncthreads();
    for (int off = 1; off < SCAN_B; off <<= 1) {
        int add = (t >= off) ? s[t - off] : 0;
        int cur = s[t];
        __syncthreads();
        s[t] = cur + add;
        __syncthreads();
    }
    int excl = s[t] - tsum;
    int base = bsums[blockIdx.x] + excl;
    if (i0     < n) outx[i0]     = base;
    if (i0 + 1 < n) outx[i0 + 1] = base + v0;
    if (i0 + 2 < n) outx[i0 + 2] = base + v0 + v1;
    if (i0 + 3 < n) outx[i0 + 3] = base + v0 + v1 + v2;
}

// after this kernel, cur[d] == row_end(d) (== row_start(d+1))
__global__ __launch_bounds__(256) void reorder_kernel(
    const int* __restrict__ idx, const float* __restrict__ orient,
    int* __restrict__ cur, unsigned* __restrict__ packed, int nadj)
{
    int e = blockIdx.x * 256 + threadIdx.x;
    if (e >= nadj) return;
    int src = idx[e];
    int dst = idx[nadj + e];
    int p = atomicAdd(&cur[dst], 1);
    packed[p] = (unsigned)src | (orient[e] < 0.f ? 0x80000000u : 0u);
}

// ---------------------------------------------------------------------------
// gather: one wave per dst row, both adjacencies; no atomics, no memset needed
// ---------------------------------------------------------------------------
__global__ __launch_bounds__(256) void gather_kernel(
    const float* __restrict__ h,
    const int* __restrict__ endU, const unsigned* __restrict__ packedU,
    const int* __restrict__ endD, const unsigned* __restrict__ packedD,
    float* __restrict__ mup, float* __restrict__ mdn, int E)
{
    int dst = (int)((blockIdx.x * 256u + threadIdx.x) >> 6);
    if (dst >= E) return;
    int f = threadIdx.x & 63;

    float accU = 0.f;
    {
        int s0 = (dst == 0) ? 0 : endU[dst - 1];
        int s1 = endU[dst];
        int n = s0;
        for (; n + 4 <= s1; n += 4) {
            unsigned p0 = packedU[n], p1 = packedU[n+1], p2 = packedU[n+2], p3 = packedU[n+3];
            float v0 = h[(size_t)(p0 & 0x7fffffffu) * H64 + f];
            float v1 = h[(size_t)(p1 & 0x7fffffffu) * H64 + f];
            float v2 = h[(size_t)(p2 & 0x7fffffffu) * H64 + f];
            float v3 = h[(size_t)(p3 & 0x7fffffffu) * H64 + f];
            accU += __uint_as_float(__float_as_uint(v0) ^ (p0 & 0x80000000u));
            accU += __uint_as_float(__float_as_uint(v1) ^ (p1 & 0x80000000u));
            accU += __uint_as_float(__float_as_uint(v2) ^ (p2 & 0x80000000u));
            accU += __uint_as_float(__float_as_uint(v3) ^ (p3 & 0x80000000u));
        }
        for (; n < s1; ++n) {
            unsigned p = packedU[n];
            float v = h[(size_t)(p & 0x7fffffffu) * H64 + f];
            accU += __uint_as_float(__float_as_uint(v) ^ (p & 0x80000000u));
        }
    }
    float accD = 0.f;
    {
        int s0 = (dst == 0) ? 0 : endD[dst - 1];
        int s1 = endD[dst];
        int n = s0;
        for (; n + 4 <= s1; n += 4) {
            unsigned p0 = packedD[n], p1 = packedD[n+1], p2 = packedD[n+2], p3 = packedD[n+3];
            float v0 = h[(size_t)(p0 & 0x7fffffffu) * H64 + f];
            float v1 = h[(size_t)(p1 & 0x7fffffffu) * H64 + f];
            float v2 = h[(size_t)(p2 & 0x7fffffffu) * H64 + f];
            float v3 = h[(size_t)(p3 & 0x7fffffffu) * H64 + f];
            accD += __uint_as_float(__float_as_uint(v0) ^ (p0 & 0x80000000u));
            accD += __uint_as_float(__float_as_uint(v1) ^ (p1 & 0x80000000u));
            accD += __uint_as_float(__float_as_uint(v2) ^ (p2 & 0x80000000u));
            accD += __uint_as_float(__float_as_uint(v3) ^ (p3 & 0x80000000u));
        }
        for (; n < s1; ++n) {
            unsigned p = packedD[n];
            float v = h[(size_t)(p & 0x7fffffffu) * H64 + f];
            accD += __uint_as_float(__float_as_uint(v) ^ (p & 0x80000000u));
        }
    }
    mup[(size_t)dst * H64 + f] = accU;
    mdn[(size_t)dst * H64 + f] = accD;
}

// ---------------------------------------------------------------------------
// fused h_out = tanh(hin @ Ws^T + mup @ Wu^T + mdn @ Wd^T)
// 256 threads, 32 rows/block; each wave keeps 8 row-accumulators so each
// Wt[k][j] LDS read is amortized over 8 rows; row reads are b128.
// ---------------------------------------------------------------------------
#define TILE_ROWS 32
__global__ __launch_bounds__(256) void gemm_tanh_kernel(
    const float* __restrict__ hin, const float* __restrict__ mup,
    const float* __restrict__ mdn,
    const float* __restrict__ Ws, const float* __restrict__ Wu,
    const float* __restrict__ Wd,
    float* __restrict__ hout, int E)
{
    __shared__ float Wt[3][64][65];           // [mat][k][j], +1 pad
    __shared__ float rows[3][TILE_ROWS][64];  // [mat][row][k]

    int tid = threadIdx.x;
    for (int i = tid; i < 4096; i += 256) {
        int j = i >> 6, k = i & 63;
        Wt[0][k][j] = Ws[i];
        Wt[1][k][j] = Wu[i];
        Wt[2][k][j] = Wd[i];
    }
    int base = blockIdx.x * TILE_ROWS;
    for (int i = tid; i < 3 * TILE_ROWS * 64; i += 256) {
        int m  = i / (TILE_ROWS * 64);
        int rr = (i >> 6) % TILE_ROWS;
        int fg = i & 63;
        int row = base + rr;
        const float* src = (m == 0) ? hin : ((m == 1) ? mup : mdn);
        rows[m][rr][fg] = (row < E) ? src[(size_t)row * H64 + fg] : 0.f;
    }
    __syncthreads();

    int r = tid >> 6;   // wave 0..3 -> rows [r*8, r*8+8)
    int j = tid & 63;
    int rr0 = r * 8;

    float acc[8];
    #pragma unroll
    for (int t = 0; t < 8; ++t) acc[t] = 0.f;

    for (int k = 0; k < 64; k += 4) {
        float4a rq0[8], rq1[8], rq2[8];
        #pragma unroll
        for (int t = 0; t < 8; ++t) {
            rq0[t] = *(const float4a*)&rows[0][rr0 + t][k];
            rq1[t] = *(const float4a*)&rows[1][rr0 + t][k];
            rq2[t] = *(const float4a*)&rows[2][rr0 + t][k];
        }
        #pragma unroll
        for (int kk = 0; kk < 4; ++kk) {
            float ws = Wt[0][k + kk][j];
            float wu = Wt[1][k + kk][j];
            float wd = Wt[2][k + kk][j];
            #pragma unroll
            for (int t = 0; t < 8; ++t) {
                acc[t] = fmaf(rq0[t][kk], ws, acc[t]);
                acc[t] = fmaf(rq1[t][kk], wu, acc[t]);
                acc[t] = fmaf(rq2[t][kk], wd, acc[t]);
            }
        }
    }

    #pragma unroll
    for (int t = 0; t < 8; ++t) {
        int row = base + rr0 + t;
        if (row < E) {
            float e2 = __expf(2.f * acc[t]);
            hout[(size_t)row * H64 + j] = 1.f - 2.f / (e2 + 1.f);
        }
    }
}

// ---------------------------------------------------------------------------
// pooled[batch[i]] += |h[i]|  (batch sorted -> register-accumulate per wave)
// ---------------------------------------------------------------------------
#define ROWS_PER_WAVE 64
__global__ __launch_bounds__(256) void pool_kernel(
    const float* __restrict__ h, const int* __restrict__ batch,
    float* __restrict__ pooled, int E)
{
    int wave = (int)((blockIdx.x * 256 + threadIdx.x) >> 6);
    int j = threadIdx.x & 63;
    int row0 = wave * ROWS_PER_WAVE;
    if (row0 >= E) return;
    int row1 = min(row0 + ROWS_PER_WAVE, E);

    int cur = batch[row0];
    float acc = 0.f;
    for (int i = row0; i < row1; ++i) {
        int b = batch[i];
        if (b != cur) {
            atomicAdd(&pooled[(size_t)cur * H64 + j], acc);
            acc = 0.f;
            cur = b;
        }
        acc += fabsf(h[(size_t)i * H64 + j]);
    }
    atomicAdd(&pooled[(size_t)cur * H64 + j], acc);
}

// ---------------------------------------------------------------------------
// head: z = relu(pooled @ lin1^T + b1); out = z @ lin2^T + b2
// ---------------------------------------------------------------------------
__global__ __launch_bounds__(64) void head_kernel(
    const float* __restrict__ pooled,
    const float* __restrict__ lin1_w, const float* __restrict__ lin1_b,
    const float* __restrict__ lin2_w, const float* __restrict__ lin2_b,
    float* __restrict__ out, int C)
{
    __shared__ float p[64];
    __shared__ float z[64];
    int b = blockIdx.x;
    int t = threadIdx.x;

    p[t] = pooled[(size_t)b * H64 + t];
    __syncthreads();

    float acc = lin1_b[t];
    #pragma unroll
    for (int k = 0; k < 64; ++k) acc += p[k] * lin1_w[t * 64 + k];
    z[t] = fmaxf(acc, 0.f);
    __syncthreads();

    if (t < C) {
        float o = lin2_b[t];
        #pragma unroll
        for (int k = 0; k < 64; ++k) o += z[k] * lin2_w[t * 64 + k];
        out[(size_t)b * C + t] = o;
    }
}

// ---------------------------------------------------------------------------
extern "C" void kernel_launch(void* const* d_in, const int* in_sizes, int n_in,
                              void* d_out, int out_size, void* d_ws, size_t ws_size,
                              hipStream_t stream)
{
    const float* x          = (const float*)d_in[0];
    const int*   up_index   = (const int*)  d_in[1];
    const float* up_orient  = (const float*)d_in[2];
    const int*   down_index = (const int*)  d_in[3];
    const float* down_orient= (const float*)d_in[4];
    const int*   batch      = (const int*)  d_in[5];
    const float* W_up       = (const float*)d_in[6];
    const float* W_down     = (const float*)d_in[7];
    const float* W_self     = (const float*)d_in[8];
    const float* lin1_w     = (const float*)d_in[9];
    const float* lin1_b     = (const float*)d_in[10];
    const float* lin2_w     = (const float*)d_in[11];
    const float* lin2_b     = (const float*)d_in[12];
    float* out = (float*)d_out;

    const int E    = in_sizes[0] / H64;
    const int NADJ = in_sizes[1] / 2;
    const int C    = in_sizes[11] / H64;
    const int B    = out_size / C;
    const int L    = in_sizes[6] / (H64 * H64);

    // ---- workspace layout (bytes): 3*E*64*4 + B*64*4 + ints (~181 MB) ----
    float* hbuf   = (float*)d_ws;                 // E*64
    float* mup    = hbuf + (size_t)E * H64;       // E*64
    float* mdn    = mup  + (size_t)E * H64;       // E*64
    float* pooled = mdn  + (size_t)E * H64;       // B*64
    int*   curU   = (int*)(pooled + (size_t)B * H64);   // E
    int*   curD   = curU + E;                            // E
    int*   deg    = curD + E;                            // E (reused U then D)
    int*   bsums  = deg + E;                             // 256
    unsigned* packedU = (unsigned*)(bsums + 256);        // NADJ
    unsigned* packedD = packedU + NADJ;                  // NADJ

    const int adj_blocks  = (NADJ + 255) / 256;
    const int nscan       = (E + SCAN_TILE - 1) / SCAN_TILE;
    const int gather_blocks = (E * 64 + 255) / 256;      // wave per row
    const int gemm_blocks   = (E + TILE_ROWS - 1) / TILE_ROWS;
    const int pool_waves    = (E + ROWS_PER_WAVE - 1) / ROWS_PER_WAVE;
    const int pool_blocks   = (pool_waves + 3) / 4;

    // ---- build CSR (by dst) for both adjacencies ----
    hipMemsetAsync(deg, 0, (size_t)E * sizeof(int), stream);
    hist_kernel<<<adj_blocks, 256, 0, stream>>>(up_index + NADJ, deg, NADJ);
    scan_partial<<<nscan, 256, 0, stream>>>(deg, bsums, E);
    scan_bsums_k<<<1, 64, 0, stream>>>(bsums, nscan);
    scan_final<<<nscan, 256, 0, stream>>>(deg, bsums, curU, E);
    reorder_kernel<<<adj_blocks, 256, 0, stream>>>(up_index, up_orient, curU, packedU, NADJ);

    hipMemsetAsync(deg, 0, (size_t)E * sizeof(int), stream);
    hist_kernel<<<adj_blocks, 256, 0, stream>>>(down_index + NADJ, deg, NADJ);
    scan_partial<<<nscan, 256, 0, stream>>>(deg, bsums, E);
    scan_bsums_k<<<1, 64, 0, stream>>>(bsums, nscan);
    scan_final<<<nscan, 256, 0, stream>>>(deg, bsums, curD, E);
    reorder_kernel<<<adj_blocks, 256, 0, stream>>>(down_index, down_orient, curD, packedD, NADJ);

    // ---- layers ----
    for (int l = 0; l < L; ++l) {
        const float* hin = (l == 0) ? x : hbuf;
        gather_kernel<<<gather_blocks, 256, 0, stream>>>(
            hin, curU, packedU, curD, packedD, mup, mdn, E);
        gemm_tanh_kernel<<<gemm_blocks, 256, 0, stream>>>(
            hin, mup, mdn,
            W_self + (size_t)l * 4096, W_up + (size_t)l * 4096, W_down + (size_t)l * 4096,
            hbuf, E);
    }

    // ---- readout ----
    hipMemsetAsync(pooled, 0, (size_t)B * H64 * sizeof(float), stream);
    pool_kernel<<<pool_blocks, 256, 0, stream>>>(hbuf, batch, pooled, E);
    head_kernel<<<B, 64, 0, stream>>>(pooled, lin1_w, lin1_b, lin2_w, lin2_b, out, C);
}

// Round 3
// 1838.890 us; speedup vs baseline: 2.7047x; 1.1464x over previous
//
#include <hip/hip_runtime.h>
#include <hip/hip_bf16.h>

#define H64 64
typedef float float4a __attribute__((ext_vector_type(4)));

__device__ __forceinline__ unsigned short f2bf(float x) {
    unsigned b = __float_as_uint(x);
    unsigned r = (b + 0x7fffu + ((b >> 16) & 1u)) >> 16;
    return (unsigned short)r;
}

// ---------------------------------------------------------------------------
// CSR build (both adjacencies concatenated: U rows [0,E), D rows [E,2E))
// ---------------------------------------------------------------------------
__global__ __launch_bounds__(256) void hist2_kernel(
    const int* __restrict__ up_dst, const int* __restrict__ dn_dst,
    int* __restrict__ deg2, int nadj, int E)
{
    int g = blockIdx.x * 256 + threadIdx.x;
    if (g < nadj) {
        atomicAdd(&deg2[up_dst[g]], 1);
    } else {
        int e = g - nadj;
        if (e < nadj) atomicAdd(&deg2[E + dn_dst[e]], 1);
    }
}

#define SCAN_B 256
#define SCAN_TILE 1024

__global__ __launch_bounds__(256) void scan_partial(
    const int* __restrict__ deg, int* __restrict__ bsums, int n)
{
    __shared__ int s[SCAN_B];
    int t = threadIdx.x;
    int i0 = blockIdx.x * SCAN_TILE + t * 4;
    int sum = 0;
    if (i0 + 3 < n) {
        int4 v = *(const int4*)(deg + i0);
        sum = v.x + v.y + v.z + v.w;
    } else {
        for (int k = 0; k < 4; ++k) if (i0 + k < n) sum += deg[i0 + k];
    }
    s[t] = sum; __syncthreads();
    for (int off = 128; off > 0; off >>= 1) {
        if (t < off) s[t] += s[t + off];
        __syncthreads();
    }
    if (t == 0) bsums[blockIdx.x] = s[0];
}

// parallel block-level exclusive scan of bsums (nblk <= 1024)
__global__ __launch_bounds__(256) void scan_bsums_k(int* bsums, int nblk)
{
    __shared__ int s[SCAN_B];
    int t = threadIdx.x;
    int i0 = t * 4;
    int v0 = 0, v1 = 0, v2 = 0, v3 = 0;
    if (i0     < nblk) v0 = bsums[i0];
    if (i0 + 1 < nblk) v1 = bsums[i0 + 1];
    if (i0 + 2 < nblk) v2 = bsums[i0 + 2];
    if (i0 + 3 < nblk) v3 = bsums[i0 + 3];
    int tsum = v0 + v1 + v2 + v3;
    s[t] = tsum; __syncthreads();
    for (int off = 1; off < SCAN_B; off <<= 1) {
        int add = (t >= off) ? s[t - off] : 0;
        int cur = s[t];
        __syncthreads();
        s[t] = cur + add;
        __syncthreads();
    }
    int excl = s[t] - tsum;
    if (i0     < nblk) bsums[i0]     = excl;
    if (i0 + 1 < nblk) bsums[i0 + 1] = excl + v0;
    if (i0 + 2 < nblk) bsums[i0 + 2] = excl + v0 + v1;
    if (i0 + 3 < nblk) bsums[i0 + 3] = excl + v0 + v1 + v2;
}

__global__ __launch_bounds__(256) void scan_final(
    const int* __restrict__ deg, const int* __restrict__ bsums,
    int* __restrict__ outx, int n)
{
    __shared__ int s[SCAN_B];
    int t = threadIdx.x;
    int i0 = blockIdx.x * SCAN_TILE + t * 4;
    int v0 = 0, v1 = 0, v2 = 0, v3 = 0;
    if (i0 + 3 < n) {
        int4 v = *(const int4*)(deg + i0);
        v0 = v.x; v1 = v.y; v2 = v.z; v3 = v.w;
    } else {
        if (i0     < n) v0 = deg[i0];
        if (i0 + 1 < n) v1 = deg[i0 + 1];
        if (i0 + 2 < n) v2 = deg[i0 + 2];
        if (i0 + 3 < n) v3 = deg[i0 + 3];
    }
    int tsum = v0 + v1 + v2 + v3;
    s[t] = tsum; __syncthreads();
    for (int off = 1; off < SCAN_B; off <<= 1) {
        int add = (t >= off) ? s[t - off] : 0;
        int cur = s[t];
        __syncthreads();
        s[t] = cur + add;
        __syncthreads();
    }
    int excl = s[t] - tsum;
    int base = bsums[blockIdx.x] + excl;
    if (i0     < n) outx[i0]     = base;
    if (i0 + 1 < n) outx[i0 + 1] = base + v0;
    if (i0 + 2 < n) outx[i0 + 2] = base + v0 + v1;
    if (i0 + 3 < n) outx[i0 + 3] = base + v0 + v1 + v2;
}

// after this kernel, end2[d] == row_end(d)
__global__ __launch_bounds__(256) void reorder2_kernel(
    const int* __restrict__ up_index, const float* __restrict__ up_orient,
    const int* __restrict__ dn_index, const float* __restrict__ dn_orient,
    int* __restrict__ end2, unsigned* __restrict__ packed2, int nadj, int E)
{
    int g = blockIdx.x * 256 + threadIdx.x;
    if (g < nadj) {
        int src = up_index[g];
        int dst = up_index[nadj + g];
        int p = atomicAdd(&end2[dst], 1);
        packed2[p] = (unsigned)src | (up_orient[g] < 0.f ? 0x80000000u : 0u);
    } else {
        int e = g - nadj;
        if (e < nadj) {
            int src = dn_index[e];
            int dst = dn_index[nadj + e];
            int p = atomicAdd(&end2[E + dst], 1);
            packed2[p] = (unsigned)src | (dn_orient[e] < 0.f ? 0x80000000u : 0u);
        }
    }
}

// ---------------------------------------------------------------------------
// f32 -> bf16 conversion (for layer-0 x)
// ---------------------------------------------------------------------------
__global__ __launch_bounds__(256) void conv_bf16_kernel(
    const float* __restrict__ x, unsigned short* __restrict__ hb, size_t n)
{
    size_t i = ((size_t)blockIdx.x * 256 + threadIdx.x) * 4;
    if (i + 3 < n) {
        float4a v = *(const float4a*)(x + i);
        uint2 o;
        o.x = (unsigned)f2bf(v[0]) | ((unsigned)f2bf(v[1]) << 16);
        o.y = (unsigned)f2bf(v[2]) | ((unsigned)f2bf(v[3]) << 16);
        *(uint2*)(hb + i) = o;
    } else {
        for (size_t k = i; k < n; ++k) hb[k] = f2bf(x[k]);
    }
}

// ---------------------------------------------------------------------------
// gather from bf16 h-copy: one wave per dst row, both adjacencies
// ---------------------------------------------------------------------------
__device__ __forceinline__ float seg_sum(
    const unsigned short* __restrict__ hb, const unsigned* __restrict__ packed2,
    int s0, int s1, int f, int lane)
{
    float acc = 0.f;
    for (int b = s0; b < s1; b += 64) {
        int cnt = min(64, s1 - b);
        unsigned pk = (lane < cnt) ? packed2[b + lane] : 0u;
        int n = 0;
        for (; n + 8 <= cnt; n += 8) {
            unsigned p[8];
            float v[8];
            #pragma unroll
            for (int t = 0; t < 8; ++t) p[t] = __shfl(pk, n + t);
            #pragma unroll
            for (int t = 0; t < 8; ++t) {
                unsigned u = hb[(size_t)(p[t] & 0x7fffffffu) * H64 + f];
                v[t] = __uint_as_float((u << 16) ^ (p[t] & 0x80000000u));
            }
            #pragma unroll
            for (int t = 0; t < 8; ++t) acc += v[t];
        }
        for (; n < cnt; ++n) {
            unsigned p = __shfl(pk, n);
            unsigned u = hb[(size_t)(p & 0x7fffffffu) * H64 + f];
            acc += __uint_as_float((u << 16) ^ (p & 0x80000000u));
        }
    }
    return acc;
}

__global__ __launch_bounds__(256) void gather_kernel(
    const unsigned short* __restrict__ hb,
    const int* __restrict__ end2, const unsigned* __restrict__ packed2,
    unsigned short* __restrict__ mupb, unsigned short* __restrict__ mdnb, int E)
{
    int dst = (int)((blockIdx.x * 256u + threadIdx.x) >> 6);
    if (dst >= E) return;
    int f = threadIdx.x & 63;
    int lane = f;

    int s0U = (dst == 0) ? 0 : end2[dst - 1];
    int s1U = end2[dst];
    float accU = seg_sum(hb, packed2, s0U, s1U, f, lane);

    int s0D = end2[E + dst - 1];
    int s1D = end2[E + dst];
    float accD = seg_sum(hb, packed2, s0D, s1D, f, lane);

    mupb[(size_t)dst * H64 + f] = f2bf(accU);
    mdnb[(size_t)dst * H64 + f] = f2bf(accD);
}

// ---------------------------------------------------------------------------
// fused h_out = tanh(hin @ Ws^T + mup @ Wu^T + mdn @ Wd^T)
// hin f32, messages bf16 (staged to f32 in LDS); writes f32 + bf16 copies
// ---------------------------------------------------------------------------
#define TILE_ROWS 32
__global__ __launch_bounds__(256) void gemm_tanh_kernel(
    const float* __restrict__ hin,
    const unsigned short* __restrict__ mupb, const unsigned short* __restrict__ mdnb,
    const float* __restrict__ Ws, const float* __restrict__ Wu,
    const float* __restrict__ Wd,
    float* __restrict__ hout, unsigned short* __restrict__ hbout, int E)
{
    __shared__ float Wt[3][64][65];           // [mat][k][j], +1 pad
    __shared__ float rows[3][TILE_ROWS][64];  // [mat][row][k]

    int tid = threadIdx.x;
    for (int i = tid; i < 4096; i += 256) {
        int j = i >> 6, k = i & 63;
        Wt[0][k][j] = Ws[i];
        Wt[1][k][j] = Wu[i];
        Wt[2][k][j] = Wd[i];
    }
    int base = blockIdx.x * TILE_ROWS;
    for (int i = tid; i < TILE_ROWS * 64; i += 256) {
        int rr = i >> 6, fg = i & 63;
        int row = base + rr;
        bool ok = (row < E);
        rows[0][rr][fg] = ok ? hin[(size_t)row * H64 + fg] : 0.f;
        unsigned uu = ok ? mupb[(size_t)row * H64 + fg] : 0u;
        unsigned dd = ok ? mdnb[(size_t)row * H64 + fg] : 0u;
        rows[1][rr][fg] = __uint_as_float(uu << 16);
        rows[2][rr][fg] = __uint_as_float(dd << 16);
    }
    __syncthreads();

    int r = tid >> 6;   // wave 0..3 -> rows [r*8, r*8+8)
    int j = tid & 63;
    int rr0 = r * 8;

    float acc[8];
    #pragma unroll
    for (int t = 0; t < 8; ++t) acc[t] = 0.f;

    for (int k = 0; k < 64; k += 4) {
        float4a rq0[8], rq1[8], rq2[8];
        #pragma unroll
        for (int t = 0; t < 8; ++t) {
            rq0[t] = *(const float4a*)&rows[0][rr0 + t][k];
            rq1[t] = *(const float4a*)&rows[1][rr0 + t][k];
            rq2[t] = *(const float4a*)&rows[2][rr0 + t][k];
        }
        #pragma unroll
        for (int kk = 0; kk < 4; ++kk) {
            float ws = Wt[0][k + kk][j];
            float wu = Wt[1][k + kk][j];
            float wd = Wt[2][k + kk][j];
            #pragma unroll
            for (int t = 0; t < 8; ++t) {
                acc[t] = fmaf(rq0[t][kk], ws, acc[t]);
                acc[t] = fmaf(rq1[t][kk], wu, acc[t]);
                acc[t] = fmaf(rq2[t][kk], wd, acc[t]);
            }
        }
    }

    #pragma unroll
    for (int t = 0; t < 8; ++t) {
        int row = base + rr0 + t;
        if (row < E) {
            float e2 = __expf(2.f * acc[t]);
            float val = 1.f - 2.f / (e2 + 1.f);
            hout[(size_t)row * H64 + j] = val;
            hbout[(size_t)row * H64 + j] = f2bf(val);
        }
    }
}

// ---------------------------------------------------------------------------
// pooled[batch[i]] += |h[i]|  (batch sorted -> register-accumulate per wave)
// ---------------------------------------------------------------------------
#define ROWS_PER_WAVE 64
__global__ __launch_bounds__(256) void pool_kernel(
    const float* __restrict__ h, const int* __restrict__ batch,
    float* __restrict__ pooled, int E)
{
    int wave = (int)((blockIdx.x * 256 + threadIdx.x) >> 6);
    int j = threadIdx.x & 63;
    int row0 = wave * ROWS_PER_WAVE;
    if (row0 >= E) return;
    int row1 = min(row0 + ROWS_PER_WAVE, E);

    int cur = batch[row0];
    float acc = 0.f;
    for (int i = row0; i < row1; ++i) {
        int b = batch[i];
        if (b != cur) {
            atomicAdd(&pooled[(size_t)cur * H64 + j], acc);
            acc = 0.f;
            cur = b;
        }
        acc += fabsf(h[(size_t)i * H64 + j]);
    }
    atomicAdd(&pooled[(size_t)cur * H64 + j], acc);
}

// ---------------------------------------------------------------------------
// head: z = relu(pooled @ lin1^T + b1); out = z @ lin2^T + b2
// ---------------------------------------------------------------------------
__global__ __launch_bounds__(64) void head_kernel(
    const float* __restrict__ pooled,
    const float* __restrict__ lin1_w, const float* __restrict__ lin1_b,
    const float* __restrict__ lin2_w, const float* __restrict__ lin2_b,
    float* __restrict__ out, int C)
{
    __shared__ float p[64];
    __shared__ float z[64];
    int b = blockIdx.x;
    int t = threadIdx.x;

    p[t] = pooled[(size_t)b * H64 + t];
    __syncthreads();

    float acc = lin1_b[t];
    #pragma unroll
    for (int k = 0; k < 64; ++k) acc += p[k] * lin1_w[t * 64 + k];
    z[t] = fmaxf(acc, 0.f);
    __syncthreads();

    if (t < C) {
        float o = lin2_b[t];
        #pragma unroll
        for (int k = 0; k < 64; ++k) o += z[k] * lin2_w[t * 64 + k];
        out[(size_t)b * C + t] = o;
    }
}

// ---------------------------------------------------------------------------
extern "C" void kernel_launch(void* const* d_in, const int* in_sizes, int n_in,
                              void* d_out, int out_size, void* d_ws, size_t ws_size,
                              hipStream_t stream)
{
    const float* x          = (const float*)d_in[0];
    const int*   up_index   = (const int*)  d_in[1];
    const float* up_orient  = (const float*)d_in[2];
    const int*   down_index = (const int*)  d_in[3];
    const float* down_orient= (const float*)d_in[4];
    const int*   batch      = (const int*)  d_in[5];
    const float* W_up       = (const float*)d_in[6];
    const float* W_down     = (const float*)d_in[7];
    const float* W_self     = (const float*)d_in[8];
    const float* lin1_w     = (const float*)d_in[9];
    const float* lin1_b     = (const float*)d_in[10];
    const float* lin2_w     = (const float*)d_in[11];
    const float* lin2_b     = (const float*)d_in[12];
    float* out = (float*)d_out;

    const int E    = in_sizes[0] / H64;
    const int NADJ = in_sizes[1] / 2;
    const int C    = in_sizes[11] / H64;
    const int B    = out_size / C;
    const int L    = in_sizes[6] / (H64 * H64);

    // ---- workspace layout (~157 MB) ----
    float*          hbuf    = (float*)d_ws;                       // E*64 f32
    unsigned short* hb      = (unsigned short*)(hbuf + (size_t)E * H64); // E*64 bf16
    unsigned short* mupb    = hb   + (size_t)E * H64;             // E*64 bf16
    unsigned short* mdnb    = mupb + (size_t)E * H64;             // E*64 bf16
    float*          pooled  = (float*)(mdnb + (size_t)E * H64);   // B*64 f32
    int*            end2    = (int*)(pooled + (size_t)B * H64);   // 2E
    int*            deg2    = end2 + (size_t)2 * E;               // 2E
    int*            bsums   = deg2 + (size_t)2 * E;               // 1024
    unsigned*       packed2 = (unsigned*)(bsums + 1024);          // 2*NADJ

    const int n2          = 2 * E;
    const int both_blocks = (2 * NADJ + 255) / 256;
    const int nscan       = (n2 + SCAN_TILE - 1) / SCAN_TILE;
    const int gather_blocks = (int)(((long long)E * 64 + 255) / 256);
    const int conv_blocks   = (int)(((long long)E * 64 / 4 + 255) / 256);
    const int gemm_blocks   = (E + TILE_ROWS - 1) / TILE_ROWS;
    const int pool_waves    = (E + ROWS_PER_WAVE - 1) / ROWS_PER_WAVE;
    const int pool_blocks   = (pool_waves + 3) / 4;

    // ---- build CSR (by dst) for both adjacencies in one concatenated pass ----
    hipMemsetAsync(deg2, 0, (size_t)n2 * sizeof(int), stream);
    hist2_kernel<<<both_blocks, 256, 0, stream>>>(up_index + NADJ, down_index + NADJ, deg2, NADJ, E);
    scan_partial<<<nscan, 256, 0, stream>>>(deg2, bsums, n2);
    scan_bsums_k<<<1, 256, 0, stream>>>(bsums, nscan);
    scan_final<<<nscan, 256, 0, stream>>>(deg2, bsums, end2, n2);
    reorder2_kernel<<<both_blocks, 256, 0, stream>>>(up_index, up_orient, down_index, down_orient,
                                                     end2, packed2, NADJ, E);

    // ---- layer-0 bf16 copy of x ----
    conv_bf16_kernel<<<conv_blocks, 256, 0, stream>>>(x, hb, (size_t)E * H64);

    // ---- layers ----
    for (int l = 0; l < L; ++l) {
        const float* hin = (l == 0) ? x : hbuf;
        gather_kernel<<<gather_blocks, 256, 0, stream>>>(hb, end2, packed2, mupb, mdnb, E);
        gemm_tanh_kernel<<<gemm_blocks, 256, 0, stream>>>(
            hin, mupb, mdnb,
            W_self + (size_t)l * 4096, W_up + (size_t)l * 4096, W_down + (size_t)l * 4096,
            hbuf, hb, E);
    }

    // ---- readout ----
    hipMemsetAsync(pooled, 0, (size_t)B * H64 * sizeof(float), stream);
    pool_kernel<<<pool_blocks, 256, 0, stream>>>(hbuf, batch, pooled, E);
    head_kernel<<<B, 64, 0, stream>>>(pooled, lin1_w, lin1_b, lin2_w, lin2_b, out, C);
}

// Round 4
// 1728.397 us; speedup vs baseline: 2.8776x; 1.0639x over previous
//
#include <hip/hip_runtime.h>
#include <hip/hip_bf16.h>

#define H64 64
typedef float float4a __attribute__((ext_vector_type(4)));

__device__ __forceinline__ unsigned short f2bf(float x) {
    unsigned b = __float_as_uint(x);
    unsigned r = (b + 0x7fffu + ((b >> 16) & 1u)) >> 16;
    return (unsigned short)r;
}

// ---------------------------------------------------------------------------
// CSR build (both adjacencies concatenated: U rows [0,E), D rows [E,2E))
// ---------------------------------------------------------------------------
__global__ __launch_bounds__(256) void hist2_kernel(
    const int* __restrict__ up_dst, const int* __restrict__ dn_dst,
    int* __restrict__ deg2, int nadj, int E)
{
    int g = blockIdx.x * 256 + threadIdx.x;
    if (g < nadj) {
        atomicAdd(&deg2[up_dst[g]], 1);
    } else {
        int e = g - nadj;
        if (e < nadj) atomicAdd(&deg2[E + dn_dst[e]], 1);
    }
}

#define SCAN_B 256
#define SCAN_TILE 1024

__global__ __launch_bounds__(256) void scan_partial(
    const int* __restrict__ deg, int* __restrict__ bsums, int n)
{
    __shared__ int s[SCAN_B];
    int t = threadIdx.x;
    int i0 = blockIdx.x * SCAN_TILE + t * 4;
    int sum = 0;
    if (i0 + 3 < n) {
        int4 v = *(const int4*)(deg + i0);
        sum = v.x + v.y + v.z + v.w;
    } else {
        for (int k = 0; k < 4; ++k) if (i0 + k < n) sum += deg[i0 + k];
    }
    s[t] = sum; __syncthreads();
    for (int off = 128; off > 0; off >>= 1) {
        if (t < off) s[t] += s[t + off];
        __syncthreads();
    }
    if (t == 0) bsums[blockIdx.x] = s[0];
}

__global__ __launch_bounds__(256) void scan_bsums_k(int* bsums, int nblk)
{
    __shared__ int s[SCAN_B];
    int t = threadIdx.x;
    int i0 = t * 4;
    int v0 = 0, v1 = 0, v2 = 0, v3 = 0;
    if (i0     < nblk) v0 = bsums[i0];
    if (i0 + 1 < nblk) v1 = bsums[i0 + 1];
    if (i0 + 2 < nblk) v2 = bsums[i0 + 2];
    if (i0 + 3 < nblk) v3 = bsums[i0 + 3];
    int tsum = v0 + v1 + v2 + v3;
    s[t] = tsum; __syncthreads();
    for (int off = 1; off < SCAN_B; off <<= 1) {
        int add = (t >= off) ? s[t - off] : 0;
        int cur = s[t];
        __syncthreads();
        s[t] = cur + add;
        __syncthreads();
    }
    int excl = s[t] - tsum;
    if (i0     < nblk) bsums[i0]     = excl;
    if (i0 + 1 < nblk) bsums[i0 + 1] = excl + v0;
    if (i0 + 2 < nblk) bsums[i0 + 2] = excl + v0 + v1;
    if (i0 + 3 < nblk) bsums[i0 + 3] = excl + v0 + v1 + v2;
}

__global__ __launch_bounds__(256) void scan_final(
    const int* __restrict__ deg, const int* __restrict__ bsums,
    int* __restrict__ outx, int n)
{
    __shared__ int s[SCAN_B];
    int t = threadIdx.x;
    int i0 = blockIdx.x * SCAN_TILE + t * 4;
    int v0 = 0, v1 = 0, v2 = 0, v3 = 0;
    if (i0 + 3 < n) {
        int4 v = *(const int4*)(deg + i0);
        v0 = v.x; v1 = v.y; v2 = v.z; v3 = v.w;
    } else {
        if (i0     < n) v0 = deg[i0];
        if (i0 + 1 < n) v1 = deg[i0 + 1];
        if (i0 + 2 < n) v2 = deg[i0 + 2];
        if (i0 + 3 < n) v3 = deg[i0 + 3];
    }
    int tsum = v0 + v1 + v2 + v3;
    s[t] = tsum; __syncthreads();
    for (int off = 1; off < SCAN_B; off <<= 1) {
        int add = (t >= off) ? s[t - off] : 0;
        int cur = s[t];
        __syncthreads();
        s[t] = cur + add;
        __syncthreads();
    }
    int excl = s[t] - tsum;
    int base = bsums[blockIdx.x] + excl;
    if (i0     < n) outx[i0]     = base;
    if (i0 + 1 < n) outx[i0 + 1] = base + v0;
    if (i0 + 2 < n) outx[i0 + 2] = base + v0 + v1;
    if (i0 + 3 < n) outx[i0 + 3] = base + v0 + v1 + v2;
}

// ---------------------------------------------------------------------------
// Two-phase binned CSR scatter
//   R1: LDS multi-split into buckets of RPB dst-rows (coalesced-run writes)
//   R2: per-bucket exact placement; random writes confined to ~65KB (L2-hot)
// entry packing: [sign:1][src:21][dst_low:10]
// ---------------------------------------------------------------------------
#define RPB       1024
#define RPB_SH    10
#define NBKT_MAX  512
#define R1_CHUNK  8192

__global__ __launch_bounds__(256) void bstart_kernel(
    const int* __restrict__ end2, int* __restrict__ gcur, int* __restrict__ bstart,
    int nbkt, int total)
{
    int b = blockIdx.x * 256 + threadIdx.x;
    if (b < nbkt) {
        int s = end2[b << RPB_SH];   // end2 holds row starts at this point
        gcur[b] = s;
        bstart[b] = s;
    }
    if (b == nbkt) bstart[b] = total;
}

__global__ __launch_bounds__(256) void bin_kernel(
    const int* __restrict__ up_index, const float* __restrict__ up_orient,
    const int* __restrict__ dn_index, const float* __restrict__ dn_orient,
    int* __restrict__ gcur, unsigned* __restrict__ binned,
    int nadj, int E, int nbkt)
{
    __shared__ unsigned sval[R1_CHUNK];
    __shared__ unsigned short sbkt[R1_CHUNK];
    __shared__ int lcnt[NBKT_MAX];
    __shared__ int goff[NBKT_MAX];
    __shared__ int lrank[NBKT_MAX];

    int t = threadIdx.x;
    for (int b = t; b < nbkt; b += 256) lcnt[b] = 0;
    __syncthreads();

    long long base = (long long)blockIdx.x * R1_CHUNK;
    int total = 2 * nadj;
    #pragma unroll 4
    for (int i = 0; i < R1_CHUNK / 256; ++i) {
        long long g = base + i * 256 + t;
        int li = i * 256 + t;
        if (g < total) {
            int src, dst2; float orient;
            if (g < nadj) {
                int e = (int)g;
                src = up_index[e]; dst2 = up_index[nadj + e]; orient = up_orient[e];
            } else {
                int e = (int)(g - nadj);
                src = dn_index[e]; dst2 = E + dn_index[nadj + e]; orient = dn_orient[e];
            }
            unsigned v = ((unsigned)src << RPB_SH) | (unsigned)(dst2 & (RPB - 1))
                       | (orient < 0.f ? 0x80000000u : 0u);
            int bk = dst2 >> RPB_SH;
            sval[li] = v;
            sbkt[li] = (unsigned short)bk;
            atomicAdd(&lcnt[bk], 1);
        } else {
            sbkt[li] = 0xFFFFu;
        }
    }
    __syncthreads();
    for (int b = t; b < nbkt; b += 256) {
        int c = lcnt[b];
        lrank[b] = 0;
        if (c > 0) goff[b] = atomicAdd(&gcur[b], c);
    }
    __syncthreads();
    #pragma unroll 4
    for (int i = 0; i < R1_CHUNK / 256; ++i) {
        int li = i * 256 + t;
        unsigned short bk = sbkt[li];
        if (bk != 0xFFFFu) {
            int r = atomicAdd(&lrank[bk], 1);
            binned[goff[bk] + r] = sval[li];
        }
    }
}

// after this kernel, end2[d] == row_end(d)
__global__ __launch_bounds__(256) void csr_fill_kernel(
    const unsigned* __restrict__ binned, const int* __restrict__ bstart,
    int* __restrict__ end2, unsigned* __restrict__ packed2)
{
    int b = blockIdx.x;
    int s0 = bstart[b], s1 = bstart[b + 1];
    int dbase = b << RPB_SH;
    int i = s0 + threadIdx.x;
    for (; i + 3 * 256 < s1; i += 4 * 256) {
        unsigned v0 = binned[i];
        unsigned v1 = binned[i + 256];
        unsigned v2 = binned[i + 512];
        unsigned v3 = binned[i + 768];
        int p0 = atomicAdd(&end2[dbase | (int)(v0 & (RPB - 1))], 1);
        int p1 = atomicAdd(&end2[dbase | (int)(v1 & (RPB - 1))], 1);
        int p2 = atomicAdd(&end2[dbase | (int)(v2 & (RPB - 1))], 1);
        int p3 = atomicAdd(&end2[dbase | (int)(v3 & (RPB - 1))], 1);
        packed2[p0] = (v0 & 0x80000000u) | ((v0 >> RPB_SH) & 0x1FFFFFu);
        packed2[p1] = (v1 & 0x80000000u) | ((v1 >> RPB_SH) & 0x1FFFFFu);
        packed2[p2] = (v2 & 0x80000000u) | ((v2 >> RPB_SH) & 0x1FFFFFu);
        packed2[p3] = (v3 & 0x80000000u) | ((v3 >> RPB_SH) & 0x1FFFFFu);
    }
    for (; i < s1; i += 256) {
        unsigned v = binned[i];
        int p = atomicAdd(&end2[dbase | (int)(v & (RPB - 1))], 1);
        packed2[p] = (v & 0x80000000u) | ((v >> RPB_SH) & 0x1FFFFFu);
    }
}

// fallback single-phase reorder (used only if nbkt > NBKT_MAX)
__global__ __launch_bounds__(256) void reorder2_kernel(
    const int* __restrict__ up_index, const float* __restrict__ up_orient,
    const int* __restrict__ dn_index, const float* __restrict__ dn_orient,
    int* __restrict__ end2, unsigned* __restrict__ packed2, int nadj, int E)
{
    int g = blockIdx.x * 256 + threadIdx.x;
    if (g < nadj) {
        int src = up_index[g];
        int dst = up_index[nadj + g];
        int p = atomicAdd(&end2[dst], 1);
        packed2[p] = (unsigned)src | (up_orient[g] < 0.f ? 0x80000000u : 0u);
    } else {
        int e = g - nadj;
        if (e < nadj) {
            int src = dn_index[e];
            int dst = dn_index[nadj + e];
            int p = atomicAdd(&end2[E + dst], 1);
            packed2[p] = (unsigned)src | (dn_orient[e] < 0.f ? 0x80000000u : 0u);
        }
    }
}

// ---------------------------------------------------------------------------
// f32 -> bf16 conversion (for layer-0 x)
// ---------------------------------------------------------------------------
__global__ __launch_bounds__(256) void conv_bf16_kernel(
    const float* __restrict__ x, unsigned short* __restrict__ hb, size_t n)
{
    size_t i = ((size_t)blockIdx.x * 256 + threadIdx.x) * 4;
    if (i + 3 < n) {
        float4a v = *(const float4a*)(x + i);
        uint2 o;
        o.x = (unsigned)f2bf(v[0]) | ((unsigned)f2bf(v[1]) << 16);
        o.y = (unsigned)f2bf(v[2]) | ((unsigned)f2bf(v[3]) << 16);
        *(uint2*)(hb + i) = o;
    } else {
        for (size_t k = i; k < n; ++k) hb[k] = f2bf(x[k]);
    }
}

// ---------------------------------------------------------------------------
// gather from bf16 h-copy: one wave per dst row, both adjacencies
// ---------------------------------------------------------------------------
__device__ __forceinline__ float seg_sum(
    const unsigned short* __restrict__ hb, const unsigned* __restrict__ packed2,
    int s0, int s1, int f, int lane)
{
    float acc = 0.f;
    for (int b = s0; b < s1; b += 64) {
        int cnt = min(64, s1 - b);
        unsigned pk = (lane < cnt) ? packed2[b + lane] : 0u;
        int n = 0;
        for (; n + 8 <= cnt; n += 8) {
            unsigned p[8];
            float v[8];
            #pragma unroll
            for (int t = 0; t < 8; ++t) p[t] = __shfl(pk, n + t);
            #pragma unroll
            for (int t = 0; t < 8; ++t) {
                unsigned u = hb[(size_t)(p[t] & 0x7fffffffu) * H64 + f];
                v[t] = __uint_as_float((u << 16) ^ (p[t] & 0x80000000u));
            }
            #pragma unroll
            for (int t = 0; t < 8; ++t) acc += v[t];
        }
        for (; n < cnt; ++n) {
            unsigned p = __shfl(pk, n);
            unsigned u = hb[(size_t)(p & 0x7fffffffu) * H64 + f];
            acc += __uint_as_float((u << 16) ^ (p & 0x80000000u));
        }
    }
    return acc;
}

__global__ __launch_bounds__(256) void gather_kernel(
    const unsigned short* __restrict__ hb,
    const int* __restrict__ end2, const unsigned* __restrict__ packed2,
    unsigned short* __restrict__ mupb, unsigned short* __restrict__ mdnb, int E)
{
    int dst = (int)((blockIdx.x * 256u + threadIdx.x) >> 6);
    if (dst >= E) return;
    int f = threadIdx.x & 63;

    int s0U = (dst == 0) ? 0 : end2[dst - 1];
    int s1U = end2[dst];
    float accU = seg_sum(hb, packed2, s0U, s1U, f, f);

    int s0D = end2[E + dst - 1];
    int s1D = end2[E + dst];
    float accD = seg_sum(hb, packed2, s0D, s1D, f, f);

    mupb[(size_t)dst * H64 + f] = f2bf(accU);
    mdnb[(size_t)dst * H64 + f] = f2bf(accD);
}

// ---------------------------------------------------------------------------
// fused h_out = tanh(hin @ Ws^T + mup @ Wu^T + mdn @ Wd^T)
// ---------------------------------------------------------------------------
#define TILE_ROWS 32
__global__ __launch_bounds__(256) void gemm_tanh_kernel(
    const float* __restrict__ hin,
    const unsigned short* __restrict__ mupb, const unsigned short* __restrict__ mdnb,
    const float* __restrict__ Ws, const float* __restrict__ Wu,
    const float* __restrict__ Wd,
    float* __restrict__ hout, unsigned short* __restrict__ hbout, int E)
{
    __shared__ float Wt[3][64][65];           // [mat][k][j], +1 pad
    __shared__ float rows[3][TILE_ROWS][64];  // [mat][row][k]

    int tid = threadIdx.x;
    for (int i = tid; i < 4096; i += 256) {
        int j = i >> 6, k = i & 63;
        Wt[0][k][j] = Ws[i];
        Wt[1][k][j] = Wu[i];
        Wt[2][k][j] = Wd[i];
    }
    int base = blockIdx.x * TILE_ROWS;
    for (int i = tid; i < TILE_ROWS * 64; i += 256) {
        int rr = i >> 6, fg = i & 63;
        int row = base + rr;
        bool ok = (row < E);
        rows[0][rr][fg] = ok ? hin[(size_t)row * H64 + fg] : 0.f;
        unsigned uu = ok ? mupb[(size_t)row * H64 + fg] : 0u;
        unsigned dd = ok ? mdnb[(size_t)row * H64 + fg] : 0u;
        rows[1][rr][fg] = __uint_as_float(uu << 16);
        rows[2][rr][fg] = __uint_as_float(dd << 16);
    }
    __syncthreads();

    int r = tid >> 6;
    int j = tid & 63;
    int rr0 = r * 8;

    float acc[8];
    #pragma unroll
    for (int t = 0; t < 8; ++t) acc[t] = 0.f;

    for (int k = 0; k < 64; k += 4) {
        float4a rq0[8], rq1[8], rq2[8];
        #pragma unroll
        for (int t = 0; t < 8; ++t) {
            rq0[t] = *(const float4a*)&rows[0][rr0 + t][k];
            rq1[t] = *(const float4a*)&rows[1][rr0 + t][k];
            rq2[t] = *(const float4a*)&rows[2][rr0 + t][k];
        }
        #pragma unroll
        for (int kk = 0; kk < 4; ++kk) {
            float ws = Wt[0][k + kk][j];
            float wu = Wt[1][k + kk][j];
            float wd = Wt[2][k + kk][j];
            #pragma unroll
            for (int t = 0; t < 8; ++t) {
                acc[t] = fmaf(rq0[t][kk], ws, acc[t]);
                acc[t] = fmaf(rq1[t][kk], wu, acc[t]);
                acc[t] = fmaf(rq2[t][kk], wd, acc[t]);
            }
        }
    }

    #pragma unroll
    for (int t = 0; t < 8; ++t) {
        int row = base + rr0 + t;
        if (row < E) {
            float e2 = __expf(2.f * acc[t]);
            float val = 1.f - 2.f / (e2 + 1.f);
            hout[(size_t)row * H64 + j] = val;
            hbout[(size_t)row * H64 + j] = f2bf(val);
        }
    }
}

// ---------------------------------------------------------------------------
#define ROWS_PER_WAVE 64
__global__ __launch_bounds__(256) void pool_kernel(
    const float* __restrict__ h, const int* __restrict__ batch,
    float* __restrict__ pooled, int E)
{
    int wave = (int)((blockIdx.x * 256 + threadIdx.x) >> 6);
    int j = threadIdx.x & 63;
    int row0 = wave * ROWS_PER_WAVE;
    if (row0 >= E) return;
    int row1 = min(row0 + ROWS_PER_WAVE, E);

    int cur = batch[row0];
    float acc = 0.f;
    for (int i = row0; i < row1; ++i) {
        int b = batch[i];
        if (b != cur) {
            atomicAdd(&pooled[(size_t)cur * H64 + j], acc);
            acc = 0.f;
            cur = b;
        }
        acc += fabsf(h[(size_t)i * H64 + j]);
    }
    atomicAdd(&pooled[(size_t)cur * H64 + j], acc);
}

// ---------------------------------------------------------------------------
__global__ __launch_bounds__(64) void head_kernel(
    const float* __restrict__ pooled,
    const float* __restrict__ lin1_w, const float* __restrict__ lin1_b,
    const float* __restrict__ lin2_w, const float* __restrict__ lin2_b,
    float* __restrict__ out, int C)
{
    __shared__ float p[64];
    __shared__ float z[64];
    int b = blockIdx.x;
    int t = threadIdx.x;

    p[t] = pooled[(size_t)b * H64 + t];
    __syncthreads();

    float acc = lin1_b[t];
    #pragma unroll
    for (int k = 0; k < 64; ++k) acc += p[k] * lin1_w[t * 64 + k];
    z[t] = fmaxf(acc, 0.f);
    __syncthreads();

    if (t < C) {
        float o = lin2_b[t];
        #pragma unroll
        for (int k = 0; k < 64; ++k) o += z[k] * lin2_w[t * 64 + k];
        out[(size_t)b * C + t] = o;
    }
}

// ---------------------------------------------------------------------------
extern "C" void kernel_launch(void* const* d_in, const int* in_sizes, int n_in,
                              void* d_out, int out_size, void* d_ws, size_t ws_size,
                              hipStream_t stream)
{
    const float* x          = (const float*)d_in[0];
    const int*   up_index   = (const int*)  d_in[1];
    const float* up_orient  = (const float*)d_in[2];
    const int*   down_index = (const int*)  d_in[3];
    const float* down_orient= (const float*)d_in[4];
    const int*   batch      = (const int*)  d_in[5];
    const float* W_up       = (const float*)d_in[6];
    const float* W_down     = (const float*)d_in[7];
    const float* W_self     = (const float*)d_in[8];
    const float* lin1_w     = (const float*)d_in[9];
    const float* lin1_b     = (const float*)d_in[10];
    const float* lin2_w     = (const float*)d_in[11];
    const float* lin2_b     = (const float*)d_in[12];
    float* out = (float*)d_out;

    const int E    = in_sizes[0] / H64;
    const int NADJ = in_sizes[1] / 2;
    const int C    = in_sizes[11] / H64;
    const int B    = out_size / C;
    const int L    = in_sizes[6] / (H64 * H64);

    // ---- workspace layout ----
    float*          hbuf    = (float*)d_ws;                       // E*64 f32
    unsigned short* hb      = (unsigned short*)(hbuf + (size_t)E * H64); // E*64 bf16
    unsigned short* mupb    = hb   + (size_t)E * H64;             // E*64 bf16
    unsigned short* mdnb    = mupb + (size_t)E * H64;             // E*64 bf16
    float*          pooled  = (float*)(mdnb + (size_t)E * H64);   // B*64 f32
    int*            end2    = (int*)(pooled + (size_t)B * H64);   // 2E
    int*            deg2    = end2 + (size_t)2 * E;               // 2E
    int*            bsums   = deg2 + (size_t)2 * E;               // 1024
    int*            gcur    = bsums + 1024;                       // NBKT_MAX
    int*            bstart  = gcur + NBKT_MAX;                    // NBKT_MAX+1
    unsigned*       packed2 = (unsigned*)(bstart + NBKT_MAX + 1); // 2*NADJ
    unsigned*       binned  = (unsigned*)hbuf;  // aliases hbuf (dead until layer-0 gemm)

    const int n2          = 2 * E;
    const int nbkt        = (n2 + RPB - 1) >> RPB_SH;
    const int both_blocks = (2 * NADJ + 255) / 256;
    const int nscan       = (n2 + SCAN_TILE - 1) / SCAN_TILE;
    const int gather_blocks = (int)(((long long)E * 64 + 255) / 256);
    const int conv_blocks   = (int)(((long long)E * 64 / 4 + 255) / 256);
    const int gemm_blocks   = (E + TILE_ROWS - 1) / TILE_ROWS;
    const int pool_waves    = (E + ROWS_PER_WAVE - 1) / ROWS_PER_WAVE;
    const int pool_blocks   = (pool_waves + 3) / 4;

    // ---- CSR build ----
    hipMemsetAsync(deg2, 0, (size_t)n2 * sizeof(int), stream);
    hist2_kernel<<<both_blocks, 256, 0, stream>>>(up_index + NADJ, down_index + NADJ, deg2, NADJ, E);
    scan_partial<<<nscan, 256, 0, stream>>>(deg2, bsums, n2);
    scan_bsums_k<<<1, 256, 0, stream>>>(bsums, nscan);
    scan_final<<<nscan, 256, 0, stream>>>(deg2, bsums, end2, n2);

    if (nbkt <= NBKT_MAX) {
        const int r1_blocks = (int)(((long long)2 * NADJ + R1_CHUNK - 1) / R1_CHUNK);
        bstart_kernel<<<(nbkt + 1 + 255) / 256, 256, 0, stream>>>(end2, gcur, bstart, nbkt, 2 * NADJ);
        bin_kernel<<<r1_blocks, 256, 0, stream>>>(up_index, up_orient, down_index, down_orient,
                                                  gcur, binned, NADJ, E, nbkt);
        csr_fill_kernel<<<nbkt, 256, 0, stream>>>(binned, bstart, end2, packed2);
    } else {
        reorder2_kernel<<<both_blocks, 256, 0, stream>>>(up_index, up_orient, down_index, down_orient,
                                                         end2, packed2, NADJ, E);
    }

    // ---- layer-0 bf16 copy of x ----
    conv_bf16_kernel<<<conv_blocks, 256, 0, stream>>>(x, hb, (size_t)E * H64);

    // ---- layers ----
    for (int l = 0; l < L; ++l) {
        const float* hin = (l == 0) ? x : hbuf;
        gather_kernel<<<gather_blocks, 256, 0, stream>>>(hb, end2, packed2, mupb, mdnb, E);
        gemm_tanh_kernel<<<gemm_blocks, 256, 0, stream>>>(
            hin, mupb, mdnb,
            W_self + (size_t)l * 4096, W_up + (size_t)l * 4096, W_down + (size_t)l * 4096,
            hbuf, hb, E);
    }

    // ---- readout ----
    hipMemsetAsync(pooled, 0, (size_t)B * H64 * sizeof(float), stream);
    pool_kernel<<<pool_blocks, 256, 0, stream>>>(hbuf, batch, pooled, E);
    head_kernel<<<B, 64, 0, stream>>>(pooled, lin1_w, lin1_b, lin2_w, lin2_b, out, C);
}

// Round 5
// 1165.583 us; speedup vs baseline: 4.2671x; 1.4829x over previous
//
#include <hip/hip_runtime.h>
#include <hip/hip_bf16.h>

#define H64 64
typedef float float4a __attribute__((ext_vector_type(4)));

__device__ __forceinline__ unsigned short f2bf(float x) {
    unsigned b = __float_as_uint(x);
    unsigned r = (b + 0x7fffu + ((b >> 16) & 1u)) >> 16;
    return (unsigned short)r;
}

#define SCAN_B 256

// ---------------------------------------------------------------------------
// Binned CSR build over concatenated row space [0,2E): U rows [0,E), D [E,2E)
//   bcount: per-bucket totals (LDS-aggregated, few global atomics)
//   bscan:  1-block scan of bucket totals -> bstart/gcur
//   bin:    LDS multi-split into bucket regions (coalesced-run writes)
//   csr_fill2: per-bucket LDS histogram + scan + cursors -> exact placement
// entry packing in binned: [sign:1][src:21][dst_low:10]
// packed2 final:           [sign:1][src:31]
// ---------------------------------------------------------------------------
#define RPB       1024
#define RPB_SH    10
#define NBKT_MAX  512
#define R1_CHUNK  8192
#define BC_CHUNK  16384

__global__ __launch_bounds__(256) void bcount_kernel(
    const int* __restrict__ up_dst, const int* __restrict__ dn_dst,
    int* __restrict__ bktcnt, int nadj, int E, int nbkt)
{
    __shared__ int lc[NBKT_MAX];
    int t = threadIdx.x;
    for (int i = t; i < nbkt; i += 256) lc[i] = 0;
    __syncthreads();
    long long base = (long long)blockIdx.x * BC_CHUNK;
    long long total = 2LL * nadj;
    for (int i = 0; i < BC_CHUNK / 256; ++i) {
        long long g = base + i * 256 + t;
        if (g < total) {
            int dst2 = (g < nadj) ? up_dst[(int)g] : E + dn_dst[(int)(g - nadj)];
            atomicAdd(&lc[dst2 >> RPB_SH], 1);
        }
    }
    __syncthreads();
    for (int i = t; i < nbkt; i += 256) {
        int c = lc[i];
        if (c) atomicAdd(&bktcnt[i], c);
    }
}

__global__ __launch_bounds__(256) void bscan_kernel(
    const int* __restrict__ bktcnt, int* __restrict__ bstart, int* __restrict__ gcur,
    int nbkt, int total)
{
    __shared__ int s[SCAN_B];
    int t = threadIdx.x;
    int i0 = t * 2;
    int v0 = (i0     < nbkt) ? bktcnt[i0]     : 0;
    int v1 = (i0 + 1 < nbkt) ? bktcnt[i0 + 1] : 0;
    int tsum = v0 + v1;
    s[t] = tsum; __syncthreads();
    for (int off = 1; off < SCAN_B; off <<= 1) {
        int add = (t >= off) ? s[t - off] : 0;
        int cur = s[t];
        __syncthreads();
        s[t] = cur + add;
        __syncthreads();
    }
    int excl = s[t] - tsum;
    if (i0     < nbkt) { bstart[i0]     = excl;      gcur[i0]     = excl; }
    if (i0 + 1 < nbkt) { bstart[i0 + 1] = excl + v0; gcur[i0 + 1] = excl + v0; }
    if (t == 0) bstart[nbkt] = total;
}

__global__ __launch_bounds__(256) void bin_kernel(
    const int* __restrict__ up_index, const float* __restrict__ up_orient,
    const int* __restrict__ dn_index, const float* __restrict__ dn_orient,
    int* __restrict__ gcur, unsigned* __restrict__ binned,
    int nadj, int E, int nbkt)
{
    __shared__ unsigned sval[R1_CHUNK];
    __shared__ unsigned short sbkt[R1_CHUNK];
    __shared__ int lcnt[NBKT_MAX];
    __shared__ int goff[NBKT_MAX];
    __shared__ int lrank[NBKT_MAX];

    int t = threadIdx.x;
    for (int b = t; b < nbkt; b += 256) lcnt[b] = 0;
    __syncthreads();

    long long base = (long long)blockIdx.x * R1_CHUNK;
    int total = 2 * nadj;
    #pragma unroll 4
    for (int i = 0; i < R1_CHUNK / 256; ++i) {
        long long g = base + i * 256 + t;
        int li = i * 256 + t;
        if (g < total) {
            int src, dst2; float orient;
            if (g < nadj) {
                int e = (int)g;
                src = up_index[e]; dst2 = up_index[nadj + e]; orient = up_orient[e];
            } else {
                int e = (int)(g - nadj);
                src = dn_index[e]; dst2 = E + dn_index[nadj + e]; orient = dn_orient[e];
            }
            unsigned v = ((unsigned)src << RPB_SH) | (unsigned)(dst2 & (RPB - 1))
                       | (orient < 0.f ? 0x80000000u : 0u);
            int bk = dst2 >> RPB_SH;
            sval[li] = v;
            sbkt[li] = (unsigned short)bk;
            atomicAdd(&lcnt[bk], 1);
        } else {
            sbkt[li] = 0xFFFFu;
        }
    }
    __syncthreads();
    for (int b = t; b < nbkt; b += 256) {
        int c = lcnt[b];
        lrank[b] = 0;
        if (c > 0) goff[b] = atomicAdd(&gcur[b], c);
    }
    __syncthreads();
    #pragma unroll 4
    for (int i = 0; i < R1_CHUNK / 256; ++i) {
        int li = i * 256 + t;
        unsigned short bk = sbkt[li];
        if (bk != 0xFFFFu) {
            int r = atomicAdd(&lrank[bk], 1);
            binned[goff[bk] + r] = sval[li];
        }
    }
}

// per-bucket exact CSR placement; all per-row atomics in LDS.
// after this kernel, end2[d] == global row_end(d).
__global__ __launch_bounds__(256) void csr_fill2_kernel(
    const unsigned* __restrict__ binned, const int* __restrict__ bstart,
    int* __restrict__ end2, unsigned* __restrict__ packed2, int n2)
{
    __shared__ int lh[RPB];
    __shared__ int lcur[RPB];
    __shared__ int s[SCAN_B];
    int b = blockIdx.x;
    int t = threadIdx.x;
    int s0 = bstart[b], s1 = bstart[b + 1];
    int dbase = b << RPB_SH;

    for (int i = t; i < RPB; i += 256) lh[i] = 0;
    __syncthreads();
    for (int i = s0 + t; i < s1; i += 256) {
        unsigned v = binned[i];
        atomicAdd(&lh[v & (RPB - 1)], 1);
    }
    __syncthreads();

    int i0 = t * 4;
    int c0 = lh[i0], c1 = lh[i0 + 1], c2 = lh[i0 + 2], c3 = lh[i0 + 3];
    int tsum = c0 + c1 + c2 + c3;
    s[t] = tsum; __syncthreads();
    for (int off = 1; off < SCAN_B; off <<= 1) {
        int add = (t >= off) ? s[t - off] : 0;
        int cur = s[t];
        __syncthreads();
        s[t] = cur + add;
        __syncthreads();
    }
    int excl = s[t] - tsum;
    lcur[i0]     = excl;
    lcur[i0 + 1] = excl + c0;
    lcur[i0 + 2] = excl + c0 + c1;
    lcur[i0 + 3] = excl + c0 + c1 + c2;
    int gd = dbase + i0;
    if (gd     < n2) end2[gd]     = s0 + excl + c0;
    if (gd + 1 < n2) end2[gd + 1] = s0 + excl + c0 + c1;
    if (gd + 2 < n2) end2[gd + 2] = s0 + excl + c0 + c1 + c2;
    if (gd + 3 < n2) end2[gd + 3] = s0 + excl + tsum;
    __syncthreads();

    for (int i = s0 + t; i < s1; i += 256) {
        unsigned v = binned[i];
        int d = (int)(v & (RPB - 1));
        int p = atomicAdd(&lcur[d], 1);
        packed2[s0 + p] = (v & 0x80000000u) | ((v >> RPB_SH) & 0x1FFFFFu);
    }
}

// ---------------------------------------------------------------------------
// fallback path (only if nbkt > NBKT_MAX): global hist + scan + random reorder
// ---------------------------------------------------------------------------
#define SCAN_TILE 1024

__global__ __launch_bounds__(256) void hist2_kernel(
    const int* __restrict__ up_dst, const int* __restrict__ dn_dst,
    int* __restrict__ deg2, int nadj, int E)
{
    int g = blockIdx.x * 256 + threadIdx.x;
    if (g < nadj) {
        atomicAdd(&deg2[up_dst[g]], 1);
    } else {
        int e = g - nadj;
        if (e < nadj) atomicAdd(&deg2[E + dn_dst[e]], 1);
    }
}

__global__ __launch_bounds__(256) void scan_partial(
    const int* __restrict__ deg, int* __restrict__ bsums, int n)
{
    __shared__ int s[SCAN_B];
    int t = threadIdx.x;
    int i0 = blockIdx.x * SCAN_TILE + t * 4;
    int sum = 0;
    if (i0 + 3 < n) {
        int4 v = *(const int4*)(deg + i0);
        sum = v.x + v.y + v.z + v.w;
    } else {
        for (int k = 0; k < 4; ++k) if (i0 + k < n) sum += deg[i0 + k];
    }
    s[t] = sum; __syncthreads();
    for (int off = 128; off > 0; off >>= 1) {
        if (t < off) s[t] += s[t + off];
        __syncthreads();
    }
    if (t == 0) bsums[blockIdx.x] = s[0];
}

__global__ __launch_bounds__(256) void scan_bsums_k(int* bsums, int nblk)
{
    __shared__ int s[SCAN_B];
    int t = threadIdx.x;
    int i0 = t * 4;
    int v0 = 0, v1 = 0, v2 = 0, v3 = 0;
    if (i0     < nblk) v0 = bsums[i0];
    if (i0 + 1 < nblk) v1 = bsums[i0 + 1];
    if (i0 + 2 < nblk) v2 = bsums[i0 + 2];
    if (i0 + 3 < nblk) v3 = bsums[i0 + 3];
    int tsum = v0 + v1 + v2 + v3;
    s[t] = tsum; __syncthreads();
    for (int off = 1; off < SCAN_B; off <<= 1) {
        int add = (t >= off) ? s[t - off] : 0;
        int cur = s[t];
        __syncthreads();
        s[t] = cur + add;
        __syncthreads();
    }
    int excl = s[t] - tsum;
    if (i0     < nblk) bsums[i0]     = excl;
    if (i0 + 1 < nblk) bsums[i0 + 1] = excl + v0;
    if (i0 + 2 < nblk) bsums[i0 + 2] = excl + v0 + v1;
    if (i0 + 3 < nblk) bsums[i0 + 3] = excl + v0 + v1 + v2;
}

__global__ __launch_bounds__(256) void scan_final(
    const int* __restrict__ deg, const int* __restrict__ bsums,
    int* __restrict__ outx, int n)
{
    __shared__ int s[SCAN_B];
    int t = threadIdx.x;
    int i0 = blockIdx.x * SCAN_TILE + t * 4;
    int v0 = 0, v1 = 0, v2 = 0, v3 = 0;
    if (i0 + 3 < n) {
        int4 v = *(const int4*)(deg + i0);
        v0 = v.x; v1 = v.y; v2 = v.z; v3 = v.w;
    } else {
        if (i0     < n) v0 = deg[i0];
        if (i0 + 1 < n) v1 = deg[i0 + 1];
        if (i0 + 2 < n) v2 = deg[i0 + 2];
        if (i0 + 3 < n) v3 = deg[i0 + 3];
    }
    int tsum = v0 + v1 + v2 + v3;
    s[t] = tsum; __syncthreads();
    for (int off = 1; off < SCAN_B; off <<= 1) {
        int add = (t >= off) ? s[t - off] : 0;
        int cur = s[t];
        __syncthreads();
        s[t] = cur + add;
        __syncthreads();
    }
    int excl = s[t] - tsum;
    int base = bsums[blockIdx.x] + excl;
    if (i0     < n) outx[i0]     = base;
    if (i0 + 1 < n) outx[i0 + 1] = base + v0;
    if (i0 + 2 < n) outx[i0 + 2] = base + v0 + v1;
    if (i0 + 3 < n) outx[i0 + 3] = base + v0 + v1 + v2;
}

__global__ __launch_bounds__(256) void reorder2_kernel(
    const int* __restrict__ up_index, const float* __restrict__ up_orient,
    const int* __restrict__ dn_index, const float* __restrict__ dn_orient,
    int* __restrict__ end2, unsigned* __restrict__ packed2, int nadj, int E)
{
    int g = blockIdx.x * 256 + threadIdx.x;
    if (g < nadj) {
        int src = up_index[g];
        int dst = up_index[nadj + g];
        int p = atomicAdd(&end2[dst], 1);
        packed2[p] = (unsigned)src | (up_orient[g] < 0.f ? 0x80000000u : 0u);
    } else {
        int e = g - nadj;
        if (e < nadj) {
            int src = dn_index[e];
            int dst = dn_index[nadj + e];
            int p = atomicAdd(&end2[E + dst], 1);
            packed2[p] = (unsigned)src | (dn_orient[e] < 0.f ? 0x80000000u : 0u);
        }
    }
}

// ---------------------------------------------------------------------------
// f32 -> bf16 conversion (for layer-0 x)
// ---------------------------------------------------------------------------
__global__ __launch_bounds__(256) void conv_bf16_kernel(
    const float* __restrict__ x, unsigned short* __restrict__ hb, size_t n)
{
    size_t i = ((size_t)blockIdx.x * 256 + threadIdx.x) * 4;
    if (i + 3 < n) {
        float4a v = *(const float4a*)(x + i);
        uint2 o;
        o.x = (unsigned)f2bf(v[0]) | ((unsigned)f2bf(v[1]) << 16);
        o.y = (unsigned)f2bf(v[2]) | ((unsigned)f2bf(v[3]) << 16);
        *(uint2*)(hb + i) = o;
    } else {
        for (size_t k = i; k < n; ++k) hb[k] = f2bf(x[k]);
    }
}

// ---------------------------------------------------------------------------
// gather from bf16 h: one wave per dst row, both adjacencies
// ---------------------------------------------------------------------------
__device__ __forceinline__ float seg_sum(
    const unsigned short* __restrict__ hb, const unsigned* __restrict__ packed2,
    int s0, int s1, int f, int lane)
{
    float acc = 0.f;
    for (int b = s0; b < s1; b += 64) {
        int cnt = min(64, s1 - b);
        unsigned pk = (lane < cnt) ? packed2[b + lane] : 0u;
        int n = 0;
        for (; n + 8 <= cnt; n += 8) {
            unsigned p[8];
            float v[8];
            #pragma unroll
            for (int t = 0; t < 8; ++t) p[t] = __shfl(pk, n + t);
            #pragma unroll
            for (int t = 0; t < 8; ++t) {
                unsigned u = hb[(size_t)(p[t] & 0x7fffffffu) * H64 + f];
                v[t] = __uint_as_float((u << 16) ^ (p[t] & 0x80000000u));
            }
            #pragma unroll
            for (int t = 0; t < 8; ++t) acc += v[t];
        }
        for (; n < cnt; ++n) {
            unsigned p = __shfl(pk, n);
            unsigned u = hb[(size_t)(p & 0x7fffffffu) * H64 + f];
            acc += __uint_as_float((u << 16) ^ (p & 0x80000000u));
        }
    }
    return acc;
}

__global__ __launch_bounds__(256) void gather_kernel(
    const unsigned short* __restrict__ hb,
    const int* __restrict__ end2, const unsigned* __restrict__ packed2,
    unsigned short* __restrict__ mupb, unsigned short* __restrict__ mdnb, int E)
{
    int dst = (int)((blockIdx.x * 256u + threadIdx.x) >> 6);
    if (dst >= E) return;
    int f = threadIdx.x & 63;

    int s0U = (dst == 0) ? 0 : end2[dst - 1];
    int s1U = end2[dst];
    float accU = seg_sum(hb, packed2, s0U, s1U, f, f);

    int s0D = end2[E + dst - 1];
    int s1D = end2[E + dst];
    float accD = seg_sum(hb, packed2, s0D, s1D, f, f);

    mupb[(size_t)dst * H64 + f] = f2bf(accU);
    mdnb[(size_t)dst * H64 + f] = f2bf(accD);
}

// ---------------------------------------------------------------------------
// fused h_out = tanh(h @ Ws^T + mup @ Wu^T + mdn @ Wd^T); all h/m in bf16,
// weights & accumulation f32. In-place on hb (each block owns its rows).
// ---------------------------------------------------------------------------
#define TILE_ROWS 32
__global__ __launch_bounds__(256) void gemm_tanh_kernel(
    const unsigned short* __restrict__ hbin,
    const unsigned short* __restrict__ mupb, const unsigned short* __restrict__ mdnb,
    const float* __restrict__ Ws, const float* __restrict__ Wu,
    const float* __restrict__ Wd,
    unsigned short* __restrict__ hbout, int E)
{
    __shared__ float Wt[3][64][65];           // [mat][k][j], +1 pad
    __shared__ float rows[3][TILE_ROWS][64];  // [mat][row][k]

    int tid = threadIdx.x;
    for (int i = tid; i < 4096; i += 256) {
        int j = i >> 6, k = i & 63;
        Wt[0][k][j] = Ws[i];
        Wt[1][k][j] = Wu[i];
        Wt[2][k][j] = Wd[i];
    }
    int base = blockIdx.x * TILE_ROWS;
    // stage 4 bf16 at a time (uint2) per array
    for (int i = tid; i < TILE_ROWS * 16; i += 256) {
        int rr = i >> 4, q = (i & 15) * 4;
        int row = base + rr;
        if (row < E) {
            size_t off = (size_t)row * H64 + q;
            uint2 a = *(const uint2*)(hbin + off);
            uint2 u = *(const uint2*)(mupb + off);
            uint2 d = *(const uint2*)(mdnb + off);
            rows[0][rr][q]     = __uint_as_float(a.x << 16);
            rows[0][rr][q + 1] = __uint_as_float(a.x & 0xFFFF0000u);
            rows[0][rr][q + 2] = __uint_as_float(a.y << 16);
            rows[0][rr][q + 3] = __uint_as_float(a.y & 0xFFFF0000u);
            rows[1][rr][q]     = __uint_as_float(u.x << 16);
            rows[1][rr][q + 1] = __uint_as_float(u.x & 0xFFFF0000u);
            rows[1][rr][q + 2] = __uint_as_float(u.y << 16);
            rows[1][rr][q + 3] = __uint_as_float(u.y & 0xFFFF0000u);
            rows[2][rr][q]     = __uint_as_float(d.x << 16);
            rows[2][rr][q + 1] = __uint_as_float(d.x & 0xFFFF0000u);
            rows[2][rr][q + 2] = __uint_as_float(d.y << 16);
            rows[2][rr][q + 3] = __uint_as_float(d.y & 0xFFFF0000u);
        } else {
            #pragma unroll
            for (int k = 0; k < 4; ++k) {
                rows[0][rr][q + k] = 0.f;
                rows[1][rr][q + k] = 0.f;
                rows[2][rr][q + k] = 0.f;
            }
        }
    }
    __syncthreads();

    int r = tid >> 6;
    int j = tid & 63;
    int rr0 = r * 8;

    float acc[8];
    #pragma unroll
    for (int t = 0; t < 8; ++t) acc[t] = 0.f;

    for (int k = 0; k < 64; k += 4) {
        float4a rq0[8], rq1[8], rq2[8];
        #pragma unroll
        for (int t = 0; t < 8; ++t) {
            rq0[t] = *(const float4a*)&rows[0][rr0 + t][k];
            rq1[t] = *(const float4a*)&rows[1][rr0 + t][k];
            rq2[t] = *(const float4a*)&rows[2][rr0 + t][k];
        }
        #pragma unroll
        for (int kk = 0; kk < 4; ++kk) {
            float ws = Wt[0][k + kk][j];
            float wu = Wt[1][k + kk][j];
            float wd = Wt[2][k + kk][j];
            #pragma unroll
            for (int t = 0; t < 8; ++t) {
                acc[t] = fmaf(rq0[t][kk], ws, acc[t]);
                acc[t] = fmaf(rq1[t][kk], wu, acc[t]);
                acc[t] = fmaf(rq2[t][kk], wd, acc[t]);
            }
        }
    }

    #pragma unroll
    for (int t = 0; t < 8; ++t) {
        int row = base + rr0 + t;
        if (row < E) {
            float e2 = __expf(2.f * acc[t]);
            float val = 1.f - 2.f / (e2 + 1.f);
            hbout[(size_t)row * H64 + j] = f2bf(val);
        }
    }
}

// ---------------------------------------------------------------------------
// pooled[batch[i]] += |h[i]| over sorted batch; h in bf16
// ---------------------------------------------------------------------------
#define ROWS_PER_WAVE 64
__global__ __launch_bounds__(256) void pool_kernel(
    const unsigned short* __restrict__ hb, const int* __restrict__ batch,
    float* __restrict__ pooled, int E)
{
    int wave = (int)((blockIdx.x * 256 + threadIdx.x) >> 6);
    int j = threadIdx.x & 63;
    int row0 = wave * ROWS_PER_WAVE;
    if (row0 >= E) return;
    int row1 = min(row0 + ROWS_PER_WAVE, E);

    int cur = batch[row0];
    float acc = 0.f;
    for (int i = row0; i < row1; ++i) {
        int b = batch[i];
        if (b != cur) {
            atomicAdd(&pooled[(size_t)cur * H64 + j], acc);
            acc = 0.f;
            cur = b;
        }
        unsigned u = hb[(size_t)i * H64 + j];
        acc += fabsf(__uint_as_float(u << 16));
    }
    atomicAdd(&pooled[(size_t)cur * H64 + j], acc);
}

// ---------------------------------------------------------------------------
__global__ __launch_bounds__(64) void head_kernel(
    const float* __restrict__ pooled,
    const float* __restrict__ lin1_w, const float* __restrict__ lin1_b,
    const float* __restrict__ lin2_w, const float* __restrict__ lin2_b,
    float* __restrict__ out, int C)
{
    __shared__ float p[64];
    __shared__ float z[64];
    int b = blockIdx.x;
    int t = threadIdx.x;

    p[t] = pooled[(size_t)b * H64 + t];
    __syncthreads();

    float acc = lin1_b[t];
    #pragma unroll
    for (int k = 0; k < 64; ++k) acc += p[k] * lin1_w[t * 64 + k];
    z[t] = fmaxf(acc, 0.f);
    __syncthreads();

    if (t < C) {
        float o = lin2_b[t];
        #pragma unroll
        for (int k = 0; k < 64; ++k) o += z[k] * lin2_w[t * 64 + k];
        out[(size_t)b * C + t] = o;
    }
}

// ---------------------------------------------------------------------------
extern "C" void kernel_launch(void* const* d_in, const int* in_sizes, int n_in,
                              void* d_out, int out_size, void* d_ws, size_t ws_size,
                              hipStream_t stream)
{
    const float* x          = (const float*)d_in[0];
    const int*   up_index   = (const int*)  d_in[1];
    const float* up_orient  = (const float*)d_in[2];
    const int*   down_index = (const int*)  d_in[3];
    const float* down_orient= (const float*)d_in[4];
    const int*   batch      = (const int*)  d_in[5];
    const float* W_up       = (const float*)d_in[6];
    const float* W_down     = (const float*)d_in[7];
    const float* W_self     = (const float*)d_in[8];
    const float* lin1_w     = (const float*)d_in[9];
    const float* lin1_b     = (const float*)d_in[10];
    const float* lin2_w     = (const float*)d_in[11];
    const float* lin2_b     = (const float*)d_in[12];
    float* out = (float*)d_out;

    const int E    = in_sizes[0] / H64;
    const int NADJ = in_sizes[1] / 2;
    const int C    = in_sizes[11] / H64;
    const int B    = out_size / C;
    const int L    = in_sizes[6] / (H64 * H64);

    // ---- workspace layout (~131 MB) ----
    unsigned short* hb      = (unsigned short*)d_ws;              // E*64 bf16
    unsigned short* mupb    = hb   + (size_t)E * H64;             // E*64 bf16
    unsigned short* mdnb    = mupb + (size_t)E * H64;             // E*64 bf16
    float*          pooled  = (float*)(mdnb + (size_t)E * H64);   // B*64 f32
    int*            end2    = (int*)(pooled + (size_t)B * H64);   // 2E
    int*            deg2    = end2 + (size_t)2 * E;               // 2E (fallback)
    int*            bsums   = deg2 + (size_t)2 * E;               // 1024 (fallback)
    int*            bktcnt  = bsums + 1024;                       // NBKT_MAX
    int*            gcur    = bktcnt + NBKT_MAX;                  // NBKT_MAX
    int*            bstart  = gcur + NBKT_MAX;                    // NBKT_MAX+1
    unsigned*       packed2 = (unsigned*)(bstart + NBKT_MAX + 1); // 2*NADJ
    unsigned*       binned  = packed2 + (size_t)2 * NADJ;         // 2*NADJ

    const int n2   = 2 * E;
    const int nbkt = (n2 + RPB - 1) >> RPB_SH;
    const int total = 2 * NADJ;
    const int gather_blocks = (int)(((long long)E * 64 + 255) / 256);
    const int conv_blocks   = (int)(((long long)E * 64 / 4 + 255) / 256);
    const int gemm_blocks   = (E + TILE_ROWS - 1) / TILE_ROWS;
    const int pool_waves    = (E + ROWS_PER_WAVE - 1) / ROWS_PER_WAVE;
    const int pool_blocks   = (pool_waves + 3) / 4;

    // ---- CSR build ----
    if (nbkt <= NBKT_MAX) {
        const int bc_blocks = (total + BC_CHUNK - 1) / BC_CHUNK;
        const int r1_blocks = (total + R1_CHUNK - 1) / R1_CHUNK;
        hipMemsetAsync(bktcnt, 0, (size_t)NBKT_MAX * sizeof(int), stream);
        bcount_kernel<<<bc_blocks, 256, 0, stream>>>(up_index + NADJ, down_index + NADJ,
                                                     bktcnt, NADJ, E, nbkt);
        bscan_kernel<<<1, 256, 0, stream>>>(bktcnt, bstart, gcur, nbkt, total);
        bin_kernel<<<r1_blocks, 256, 0, stream>>>(up_index, up_orient, down_index, down_orient,
                                                  gcur, binned, NADJ, E, nbkt);
        csr_fill2_kernel<<<nbkt, 256, 0, stream>>>(binned, bstart, end2, packed2, n2);
    } else {
        const int both_blocks = (total + 255) / 256;
        const int nscan = (n2 + SCAN_TILE - 1) / SCAN_TILE;
        hipMemsetAsync(deg2, 0, (size_t)n2 * sizeof(int), stream);
        hist2_kernel<<<both_blocks, 256, 0, stream>>>(up_index + NADJ, down_index + NADJ, deg2, NADJ, E);
        scan_partial<<<nscan, 256, 0, stream>>>(deg2, bsums, n2);
        scan_bsums_k<<<1, 256, 0, stream>>>(bsums, nscan);
        scan_final<<<nscan, 256, 0, stream>>>(deg2, bsums, end2, n2);
        reorder2_kernel<<<both_blocks, 256, 0, stream>>>(up_index, up_orient, down_index, down_orient,
                                                         end2, packed2, NADJ, E);
    }

    // ---- layer-0 bf16 copy of x ----
    conv_bf16_kernel<<<conv_blocks, 256, 0, stream>>>(x, hb, (size_t)E * H64);

    // ---- layers (all state in hb, bf16) ----
    for (int l = 0; l < L; ++l) {
        gather_kernel<<<gather_blocks, 256, 0, stream>>>(hb, end2, packed2, mupb, mdnb, E);
        gemm_tanh_kernel<<<gemm_blocks, 256, 0, stream>>>(
            hb, mupb, mdnb,
            W_self + (size_t)l * 4096, W_up + (size_t)l * 4096, W_down + (size_t)l * 4096,
            hb, E);
    }

    // ---- readout ----
    hipMemsetAsync(pooled, 0, (size_t)B * H64 * sizeof(float), stream);
    pool_kernel<<<pool_blocks, 256, 0, stream>>>(hb, batch, pooled, E);
    head_kernel<<<B, 64, 0, stream>>>(pooled, lin1_w, lin1_b, lin2_w, lin2_b, out, C);
}

// Round 6
// 813.423 us; speedup vs baseline: 6.1145x; 1.4329x over previous
//
#include <hip/hip_runtime.h>
#include <hip/hip_bf16.h>

#define H64 64
typedef float float4a __attribute__((ext_vector_type(4)));
typedef float f32x4  __attribute__((ext_vector_type(4)));
typedef short bf16x8 __attribute__((ext_vector_type(8)));

__device__ __forceinline__ unsigned short f2bf(float x) {
    unsigned b = __float_as_uint(x);
    unsigned r = (b + 0x7fffu + ((b >> 16) & 1u)) >> 16;
    return (unsigned short)r;
}

#define SCAN_B 256

// ---------------------------------------------------------------------------
// Binned CSR build over concatenated row space [0,2E): U rows [0,E), D [E,2E)
// entry packing in binned: [sign:1][src:21][dst_low:10]
// packed2 final:           [sign:1][src:31]
// ---------------------------------------------------------------------------
#define RPB       1024
#define RPB_SH    10
#define NBKT_MAX  512
#define R1_CHUNK  8192
#define BC_CHUNK  16384

__global__ __launch_bounds__(256) void bcount_kernel(
    const int* __restrict__ up_dst, const int* __restrict__ dn_dst,
    int* __restrict__ bktcnt, int nadj, int E, int nbkt)
{
    __shared__ int lc[NBKT_MAX];
    int t = threadIdx.x;
    for (int i = t; i < nbkt; i += 256) lc[i] = 0;
    __syncthreads();
    long long base = (long long)blockIdx.x * BC_CHUNK;
    long long total = 2LL * nadj;
    for (int i = 0; i < BC_CHUNK / 256; ++i) {
        long long g = base + i * 256 + t;
        if (g < total) {
            int dst2 = (g < nadj) ? up_dst[(int)g] : E + dn_dst[(int)(g - nadj)];
            atomicAdd(&lc[dst2 >> RPB_SH], 1);
        }
    }
    __syncthreads();
    for (int i = t; i < nbkt; i += 256) {
        int c = lc[i];
        if (c) atomicAdd(&bktcnt[i], c);
    }
}

__global__ __launch_bounds__(256) void bscan_kernel(
    const int* __restrict__ bktcnt, int* __restrict__ bstart, int* __restrict__ gcur,
    int nbkt, int total)
{
    __shared__ int s[SCAN_B];
    int t = threadIdx.x;
    int i0 = t * 2;
    int v0 = (i0     < nbkt) ? bktcnt[i0]     : 0;
    int v1 = (i0 + 1 < nbkt) ? bktcnt[i0 + 1] : 0;
    int tsum = v0 + v1;
    s[t] = tsum; __syncthreads();
    for (int off = 1; off < SCAN_B; off <<= 1) {
        int add = (t >= off) ? s[t - off] : 0;
        int cur = s[t];
        __syncthreads();
        s[t] = cur + add;
        __syncthreads();
    }
    int excl = s[t] - tsum;
    if (i0     < nbkt) { bstart[i0]     = excl;      gcur[i0]     = excl; }
    if (i0 + 1 < nbkt) { bstart[i0 + 1] = excl + v0; gcur[i0 + 1] = excl + v0; }
    if (t == 0) bstart[nbkt] = total;
}

__global__ __launch_bounds__(256) void bin_kernel(
    const int* __restrict__ up_index, const float* __restrict__ up_orient,
    const int* __restrict__ dn_index, const float* __restrict__ dn_orient,
    int* __restrict__ gcur, unsigned* __restrict__ binned,
    int nadj, int E, int nbkt)
{
    __shared__ unsigned sval[R1_CHUNK];
    __shared__ unsigned short sbkt[R1_CHUNK];
    __shared__ int lcnt[NBKT_MAX];
    __shared__ int goff[NBKT_MAX];
    __shared__ int lrank[NBKT_MAX];

    int t = threadIdx.x;
    for (int b = t; b < nbkt; b += 256) lcnt[b] = 0;
    __syncthreads();

    long long base = (long long)blockIdx.x * R1_CHUNK;
    int total = 2 * nadj;
    #pragma unroll 4
    for (int i = 0; i < R1_CHUNK / 256; ++i) {
        long long g = base + i * 256 + t;
        int li = i * 256 + t;
        if (g < total) {
            int src, dst2; float orient;
            if (g < nadj) {
                int e = (int)g;
                src = up_index[e]; dst2 = up_index[nadj + e]; orient = up_orient[e];
            } else {
                int e = (int)(g - nadj);
                src = dn_index[e]; dst2 = E + dn_index[nadj + e]; orient = dn_orient[e];
            }
            unsigned v = ((unsigned)src << RPB_SH) | (unsigned)(dst2 & (RPB - 1))
                       | (orient < 0.f ? 0x80000000u : 0u);
            int bk = dst2 >> RPB_SH;
            sval[li] = v;
            sbkt[li] = (unsigned short)bk;
            atomicAdd(&lcnt[bk], 1);
        } else {
            sbkt[li] = 0xFFFFu;
        }
    }
    __syncthreads();
    for (int b = t; b < nbkt; b += 256) {
        int c = lcnt[b];
        lrank[b] = 0;
        if (c > 0) goff[b] = atomicAdd(&gcur[b], c);
    }
    __syncthreads();
    #pragma unroll 4
    for (int i = 0; i < R1_CHUNK / 256; ++i) {
        int li = i * 256 + t;
        unsigned short bk = sbkt[li];
        if (bk != 0xFFFFu) {
            int r = atomicAdd(&lrank[bk], 1);
            binned[goff[bk] + r] = sval[li];
        }
    }
}

// per-bucket exact CSR placement; all per-row atomics in LDS.
// after this kernel, end2[d] == global row_end(d).
__global__ __launch_bounds__(256) void csr_fill2_kernel(
    const unsigned* __restrict__ binned, const int* __restrict__ bstart,
    int* __restrict__ end2, unsigned* __restrict__ packed2, int n2)
{
    __shared__ int lh[RPB];
    __shared__ int lcur[RPB];
    __shared__ int s[SCAN_B];
    int b = blockIdx.x;
    int t = threadIdx.x;
    int s0 = bstart[b], s1 = bstart[b + 1];
    int dbase = b << RPB_SH;

    for (int i = t; i < RPB; i += 256) lh[i] = 0;
    __syncthreads();
    for (int i = s0 + t; i < s1; i += 256) {
        unsigned v = binned[i];
        atomicAdd(&lh[v & (RPB - 1)], 1);
    }
    __syncthreads();

    int i0 = t * 4;
    int c0 = lh[i0], c1 = lh[i0 + 1], c2 = lh[i0 + 2], c3 = lh[i0 + 3];
    int tsum = c0 + c1 + c2 + c3;
    s[t] = tsum; __syncthreads();
    for (int off = 1; off < SCAN_B; off <<= 1) {
        int add = (t >= off) ? s[t - off] : 0;
        int cur = s[t];
        __syncthreads();
        s[t] = cur + add;
        __syncthreads();
    }
    int excl = s[t] - tsum;
    lcur[i0]     = excl;
    lcur[i0 + 1] = excl + c0;
    lcur[i0 + 2] = excl + c0 + c1;
    lcur[i0 + 3] = excl + c0 + c1 + c2;
    int gd = dbase + i0;
    if (gd     < n2) end2[gd]     = s0 + excl + c0;
    if (gd + 1 < n2) end2[gd + 1] = s0 + excl + c0 + c1;
    if (gd + 2 < n2) end2[gd + 2] = s0 + excl + c0 + c1 + c2;
    if (gd + 3 < n2) end2[gd + 3] = s0 + excl + tsum;
    __syncthreads();

    for (int i = s0 + t; i < s1; i += 256) {
        unsigned v = binned[i];
        int d = (int)(v & (RPB - 1));
        int p = atomicAdd(&lcur[d], 1);
        packed2[s0 + p] = (v & 0x80000000u) | ((v >> RPB_SH) & 0x1FFFFFu);
    }
}

// ---------------------------------------------------------------------------
// fallback path (only if nbkt > NBKT_MAX)
// ---------------------------------------------------------------------------
#define SCAN_TILE 1024

__global__ __launch_bounds__(256) void hist2_kernel(
    const int* __restrict__ up_dst, const int* __restrict__ dn_dst,
    int* __restrict__ deg2, int nadj, int E)
{
    int g = blockIdx.x * 256 + threadIdx.x;
    if (g < nadj) {
        atomicAdd(&deg2[up_dst[g]], 1);
    } else {
        int e = g - nadj;
        if (e < nadj) atomicAdd(&deg2[E + dn_dst[e]], 1);
    }
}

__global__ __launch_bounds__(256) void scan_partial(
    const int* __restrict__ deg, int* __restrict__ bsums, int n)
{
    __shared__ int s[SCAN_B];
    int t = threadIdx.x;
    int i0 = blockIdx.x * SCAN_TILE + t * 4;
    int sum = 0;
    if (i0 + 3 < n) {
        int4 v = *(const int4*)(deg + i0);
        sum = v.x + v.y + v.z + v.w;
    } else {
        for (int k = 0; k < 4; ++k) if (i0 + k < n) sum += deg[i0 + k];
    }
    s[t] = sum; __syncthreads();
    for (int off = 128; off > 0; off >>= 1) {
        if (t < off) s[t] += s[t + off];
        __syncthreads();
    }
    if (t == 0) bsums[blockIdx.x] = s[0];
}

__global__ __launch_bounds__(256) void scan_bsums_k(int* bsums, int nblk)
{
    __shared__ int s[SCAN_B];
    int t = threadIdx.x;
    int i0 = t * 4;
    int v0 = 0, v1 = 0, v2 = 0, v3 = 0;
    if (i0     < nblk) v0 = bsums[i0];
    if (i0 + 1 < nblk) v1 = bsums[i0 + 1];
    if (i0 + 2 < nblk) v2 = bsums[i0 + 2];
    if (i0 + 3 < nblk) v3 = bsums[i0 + 3];
    int tsum = v0 + v1 + v2 + v3;
    s[t] = tsum; __syncthreads();
    for (int off = 1; off < SCAN_B; off <<= 1) {
        int add = (t >= off) ? s[t - off] : 0;
        int cur = s[t];
        __syncthreads();
        s[t] = cur + add;
        __syncthreads();
    }
    int excl = s[t] - tsum;
    if (i0     < nblk) bsums[i0]     = excl;
    if (i0 + 1 < nblk) bsums[i0 + 1] = excl + v0;
    if (i0 + 2 < nblk) bsums[i0 + 2] = excl + v0 + v1;
    if (i0 + 3 < nblk) bsums[i0 + 3] = excl + v0 + v1 + v2;
}

__global__ __launch_bounds__(256) void scan_final(
    const int* __restrict__ deg, const int* __restrict__ bsums,
    int* __restrict__ outx, int n)
{
    __shared__ int s[SCAN_B];
    int t = threadIdx.x;
    int i0 = blockIdx.x * SCAN_TILE + t * 4;
    int v0 = 0, v1 = 0, v2 = 0, v3 = 0;
    if (i0 + 3 < n) {
        int4 v = *(const int4*)(deg + i0);
        v0 = v.x; v1 = v.y; v2 = v.z; v3 = v.w;
    } else {
        if (i0     < n) v0 = deg[i0];
        if (i0 + 1 < n) v1 = deg[i0 + 1];
        if (i0 + 2 < n) v2 = deg[i0 + 2];
        if (i0 + 3 < n) v3 = deg[i0 + 3];
    }
    int tsum = v0 + v1 + v2 + v3;
    s[t] = tsum; __syncthreads();
    for (int off = 1; off < SCAN_B; off <<= 1) {
        int add = (t >= off) ? s[t - off] : 0;
        int cur = s[t];
        __syncthreads();
        s[t] = cur + add;
        __syncthreads();
    }
    int excl = s[t] - tsum;
    int base = bsums[blockIdx.x] + excl;
    if (i0     < n) outx[i0]     = base;
    if (i0 + 1 < n) outx[i0 + 1] = base + v0;
    if (i0 + 2 < n) outx[i0 + 2] = base + v0 + v1;
    if (i0 + 3 < n) outx[i0 + 3] = base + v0 + v1 + v2;
}

__global__ __launch_bounds__(256) void reorder2_kernel(
    const int* __restrict__ up_index, const float* __restrict__ up_orient,
    const int* __restrict__ dn_index, const float* __restrict__ dn_orient,
    int* __restrict__ end2, unsigned* __restrict__ packed2, int nadj, int E)
{
    int g = blockIdx.x * 256 + threadIdx.x;
    if (g < nadj) {
        int src = up_index[g];
        int dst = up_index[nadj + g];
        int p = atomicAdd(&end2[dst], 1);
        packed2[p] = (unsigned)src | (up_orient[g] < 0.f ? 0x80000000u : 0u);
    } else {
        int e = g - nadj;
        if (e < nadj) {
            int src = dn_index[e];
            int dst = dn_index[nadj + e];
            int p = atomicAdd(&end2[E + dst], 1);
            packed2[p] = (unsigned)src | (dn_orient[e] < 0.f ? 0x80000000u : 0u);
        }
    }
}

// ---------------------------------------------------------------------------
// f32 -> bf16 conversions
// ---------------------------------------------------------------------------
__global__ __launch_bounds__(256) void conv_bf16_kernel(
    const float* __restrict__ x, unsigned short* __restrict__ hb, size_t n)
{
    size_t i = ((size_t)blockIdx.x * 256 + threadIdx.x) * 4;
    if (i + 3 < n) {
        float4a v = *(const float4a*)(x + i);
        uint2 o;
        o.x = (unsigned)f2bf(v[0]) | ((unsigned)f2bf(v[1]) << 16);
        o.y = (unsigned)f2bf(v[2]) | ((unsigned)f2bf(v[3]) << 16);
        *(uint2*)(hb + i) = o;
    } else {
        for (size_t k = i; k < n; ++k) hb[k] = f2bf(x[k]);
    }
}

// Wb layout: [l][mat(0=self,1=up,2=dn)][j][k] bf16
__global__ __launch_bounds__(256) void convW_kernel(
    const float* __restrict__ Ws, const float* __restrict__ Wu,
    const float* __restrict__ Wd, unsigned short* __restrict__ Wb, int L)
{
    int i = blockIdx.x * 256 + threadIdx.x;
    int total = L * 3 * 4096;
    if (i >= total) return;
    int l = i / (3 * 4096);
    int m = (i / 4096) % 3;
    int r = i & 4095;
    const float* src = (m == 0) ? Ws : ((m == 1) ? Wu : Wd);
    Wb[i] = f2bf(src[l * 4096 + r]);
}

// ---------------------------------------------------------------------------
// gather (pair-vectorized): wave per dst row; lane loads uint (2 bf16 feats);
// lanes 0-31 process even entries, 32-63 odd; combine via shfl_xor(32).
// ---------------------------------------------------------------------------
__device__ __forceinline__ void seg_sum2(
    const unsigned* __restrict__ hb32, const unsigned* __restrict__ packed2,
    int s0, int s1, int fp, int g, int lane, float& r0, float& r1)
{
    float a0 = 0.f, a1 = 0.f;
    for (int b = s0; b < s1; b += 64) {
        int cnt = min(64, s1 - b);
        unsigned pk = (lane < cnt) ? packed2[b + lane] : 0u;
        int n = 0;
        for (; n + 8 <= cnt; n += 8) {
            unsigned pe[4], u[4];
            #pragma unroll
            for (int t = 0; t < 4; ++t) pe[t] = __shfl(pk, n + 2 * t + g);
            #pragma unroll
            for (int t = 0; t < 4; ++t)
                u[t] = hb32[(size_t)(pe[t] & 0x7fffffffu) * 32 + fp];
            #pragma unroll
            for (int t = 0; t < 4; ++t) {
                unsigned s = pe[t] & 0x80000000u;
                unsigned x = u[t] ^ (s | (s >> 16));
                a0 += __uint_as_float(x << 16);
                a1 += __uint_as_float(x & 0xFFFF0000u);
            }
        }
        for (; n < cnt; n += 2) {
            int idx = n + g;
            bool valid = idx < cnt;
            unsigned pe = __shfl(pk, valid ? idx : n);
            if (valid) {
                unsigned x = hb32[(size_t)(pe & 0x7fffffffu) * 32 + fp];
                unsigned s = pe & 0x80000000u;
                x ^= (s | (s >> 16));
                a0 += __uint_as_float(x << 16);
                a1 += __uint_as_float(x & 0xFFFF0000u);
            }
        }
    }
    r0 = a0; r1 = a1;
}

__global__ __launch_bounds__(256) void gather_kernel(
    const unsigned* __restrict__ hb32,
    const int* __restrict__ end2, const unsigned* __restrict__ packed2,
    unsigned* __restrict__ mup32, unsigned* __restrict__ mdn32, int E)
{
    int dst = (int)((blockIdx.x * 256u + threadIdx.x) >> 6);
    if (dst >= E) return;
    int lane = threadIdx.x & 63;
    int g  = lane >> 5;
    int fp = lane & 31;

    int s0U = (dst == 0) ? 0 : end2[dst - 1];
    int s1U = end2[dst];
    float u0, u1;
    seg_sum2(hb32, packed2, s0U, s1U, fp, g, lane, u0, u1);

    int s0D = end2[E + dst - 1];
    int s1D = end2[E + dst];
    float d0, d1;
    seg_sum2(hb32, packed2, s0D, s1D, fp, g, lane, d0, d1);

    u0 += __shfl_xor(u0, 32); u1 += __shfl_xor(u1, 32);
    d0 += __shfl_xor(d0, 32); d1 += __shfl_xor(d1, 32);

    unsigned valU = (unsigned)f2bf(u0) | ((unsigned)f2bf(u1) << 16);
    unsigned valD = (unsigned)f2bf(d0) | ((unsigned)f2bf(d1) << 16);
    unsigned* ptr = g ? mdn32 : mup32;
    ptr[(size_t)dst * 32 + fp] = g ? valD : valU;
}

// ---------------------------------------------------------------------------
// MFMA gemm+tanh: hb = tanh(hb@Ws^T + mup@Wu^T + mdn@Wd^T), all bf16 in/out.
// One wave per 16 rows; 24 x mfma_f32_16x16x32_bf16; zero LDS.
// k-slot mapping (lane>>4)*8+j used consistently for A and B (bijection -> OK);
// C/D: col = lane&15, row = (lane>>4)*4 + reg  [HW-verified layout].
// ---------------------------------------------------------------------------
__global__ __launch_bounds__(256) void gemm_tanh_mfma(
    const unsigned short* __restrict__ hbin,
    const unsigned short* __restrict__ mupb, const unsigned short* __restrict__ mdnb,
    const unsigned short* __restrict__ Wb,   // [3][64][64] bf16 for this layer
    unsigned short* __restrict__ hbout, int E, int nblk16)
{
    int wid  = (blockIdx.x * 256 + threadIdx.x) >> 6;
    if (wid >= nblk16) return;
    int lane = threadIdx.x & 63;
    int lg = lane >> 4;      // 0..3
    int lr = lane & 15;      // 0..15

    // B-frags: B[k][j] = W[j][k]; for (mat, jt, ks): j = jt*16+lr, k = ks*32+lg*8+t
    bf16x8 bfr[3][4][2];
    #pragma unroll
    for (int m = 0; m < 3; ++m)
        #pragma unroll
        for (int jt = 0; jt < 4; ++jt)
            #pragma unroll
            for (int ks = 0; ks < 2; ++ks)
                bfr[m][jt][ks] = *(const bf16x8*)(Wb + m * 4096 + (jt * 16 + lr) * 64 + ks * 32 + lg * 8);

    int base = wid * 16;
    int arow = base + lr;
    bool ok = (arow < E);
    size_t aoff = (size_t)arow * H64 + lg * 8;

    bf16x8 afr[3][2];
    bf16x8 zz = {0, 0, 0, 0, 0, 0, 0, 0};
    #pragma unroll
    for (int ks = 0; ks < 2; ++ks) {
        afr[0][ks] = ok ? *(const bf16x8*)(hbin + aoff + ks * 32) : zz;
        afr[1][ks] = ok ? *(const bf16x8*)(mupb + aoff + ks * 32) : zz;
        afr[2][ks] = ok ? *(const bf16x8*)(mdnb + aoff + ks * 32) : zz;
    }

    f32x4 acc[4];
    #pragma unroll
    for (int jt = 0; jt < 4; ++jt) acc[jt] = (f32x4){0.f, 0.f, 0.f, 0.f};

    #pragma unroll
    for (int m = 0; m < 3; ++m)
        #pragma unroll
        for (int ks = 0; ks < 2; ++ks)
            #pragma unroll
            for (int jt = 0; jt < 4; ++jt)
                acc[jt] = __builtin_amdgcn_mfma_f32_16x16x32_bf16(
                    afr[m][ks], bfr[m][jt][ks], acc[jt], 0, 0, 0);

    #pragma unroll
    for (int jt = 0; jt < 4; ++jt) {
        #pragma unroll
        for (int reg = 0; reg < 4; ++reg) {
            int row = base + lg * 4 + reg;
            if (row < E) {
                float v = acc[jt][reg];
                float e2 = __expf(2.f * v);
                float val = 1.f - 2.f / (e2 + 1.f);
                hbout[(size_t)row * H64 + jt * 16 + lr] = f2bf(val);
            }
        }
    }
}

// ---------------------------------------------------------------------------
// pooled[batch[i]] += |h[i]| over sorted batch; h in bf16
// ---------------------------------------------------------------------------
#define ROWS_PER_WAVE 64
__global__ __launch_bounds__(256) void pool_kernel(
    const unsigned short* __restrict__ hb, const int* __restrict__ batch,
    float* __restrict__ pooled, int E)
{
    int wave = (int)((blockIdx.x * 256 + threadIdx.x) >> 6);
    int j = threadIdx.x & 63;
    int row0 = wave * ROWS_PER_WAVE;
    if (row0 >= E) return;
    int row1 = min(row0 + ROWS_PER_WAVE, E);

    int cur = batch[row0];
    float acc = 0.f;
    for (int i = row0; i < row1; ++i) {
        int b = batch[i];
        if (b != cur) {
            atomicAdd(&pooled[(size_t)cur * H64 + j], acc);
            acc = 0.f;
            cur = b;
        }
        unsigned u = hb[(size_t)i * H64 + j];
        acc += fabsf(__uint_as_float(u << 16));
    }
    atomicAdd(&pooled[(size_t)cur * H64 + j], acc);
}

// ---------------------------------------------------------------------------
__global__ __launch_bounds__(64) void head_kernel(
    const float* __restrict__ pooled,
    const float* __restrict__ lin1_w, const float* __restrict__ lin1_b,
    const float* __restrict__ lin2_w, const float* __restrict__ lin2_b,
    float* __restrict__ out, int C)
{
    __shared__ float p[64];
    __shared__ float z[64];
    int b = blockIdx.x;
    int t = threadIdx.x;

    p[t] = pooled[(size_t)b * H64 + t];
    __syncthreads();

    float acc = lin1_b[t];
    #pragma unroll
    for (int k = 0; k < 64; ++k) acc += p[k] * lin1_w[t * 64 + k];
    z[t] = fmaxf(acc, 0.f);
    __syncthreads();

    if (t < C) {
        float o = lin2_b[t];
        #pragma unroll
        for (int k = 0; k < 64; ++k) o += z[k] * lin2_w[t * 64 + k];
        out[(size_t)b * C + t] = o;
    }
}

// ---------------------------------------------------------------------------
extern "C" void kernel_launch(void* const* d_in, const int* in_sizes, int n_in,
                              void* d_out, int out_size, void* d_ws, size_t ws_size,
                              hipStream_t stream)
{
    const float* x          = (const float*)d_in[0];
    const int*   up_index   = (const int*)  d_in[1];
    const float* up_orient  = (const float*)d_in[2];
    const int*   down_index = (const int*)  d_in[3];
    const float* down_orient= (const float*)d_in[4];
    const int*   batch      = (const int*)  d_in[5];
    const float* W_up       = (const float*)d_in[6];
    const float* W_down     = (const float*)d_in[7];
    const float* W_self     = (const float*)d_in[8];
    const float* lin1_w     = (const float*)d_in[9];
    const float* lin1_b     = (const float*)d_in[10];
    const float* lin2_w     = (const float*)d_in[11];
    const float* lin2_b     = (const float*)d_in[12];
    float* out = (float*)d_out;

    const int E    = in_sizes[0] / H64;
    const int NADJ = in_sizes[1] / 2;
    const int C    = in_sizes[11] / H64;
    const int B    = out_size / C;
    const int L    = in_sizes[6] / (H64 * H64);

    // ---- workspace layout ----
    unsigned short* hb      = (unsigned short*)d_ws;              // E*64 bf16
    unsigned short* mupb    = hb   + (size_t)E * H64;             // E*64 bf16
    unsigned short* mdnb    = mupb + (size_t)E * H64;             // E*64 bf16
    float*          pooled  = (float*)(mdnb + (size_t)E * H64);   // B*64 f32
    int*            end2    = (int*)(pooled + (size_t)B * H64);   // 2E
    int*            deg2    = end2 + (size_t)2 * E;               // 2E (fallback)
    int*            bsums   = deg2 + (size_t)2 * E;               // 1024 (fallback)
    int*            bktcnt  = bsums + 1024;                       // NBKT_MAX
    int*            gcur    = bktcnt + NBKT_MAX;                  // NBKT_MAX
    int*            bstart  = gcur + NBKT_MAX;                    // NBKT_MAX+1
    unsigned short* Wb      = (unsigned short*)(bstart + NBKT_MAX + 1); // L*3*4096 bf16
    unsigned*       packed2 = (unsigned*)(Wb + (size_t)L * 3 * 4096);   // 2*NADJ
    unsigned*       binned  = packed2 + (size_t)2 * NADJ;         // 2*NADJ

    const int n2    = 2 * E;
    const int nbkt  = (n2 + RPB - 1) >> RPB_SH;
    const int total = 2 * NADJ;
    const int gather_blocks = (int)(((long long)E * 64 + 255) / 256);
    const int conv_blocks   = (int)(((long long)E * H64 / 4 + 255) / 256);
    const int nblk16        = (E + 15) / 16;
    const int gemm_blocks   = (nblk16 + 3) / 4;
    const int convw_blocks  = (L * 3 * 4096 + 255) / 256;
    const int pool_waves    = (E + ROWS_PER_WAVE - 1) / ROWS_PER_WAVE;
    const int pool_blocks   = (pool_waves + 3) / 4;

    // ---- CSR build ----
    if (nbkt <= NBKT_MAX) {
        const int bc_blocks = (total + BC_CHUNK - 1) / BC_CHUNK;
        const int r1_blocks = (total + R1_CHUNK - 1) / R1_CHUNK;
        hipMemsetAsync(bktcnt, 0, (size_t)NBKT_MAX * sizeof(int), stream);
        bcount_kernel<<<bc_blocks, 256, 0, stream>>>(up_index + NADJ, down_index + NADJ,
                                                     bktcnt, NADJ, E, nbkt);
        bscan_kernel<<<1, 256, 0, stream>>>(bktcnt, bstart, gcur, nbkt, total);
        bin_kernel<<<r1_blocks, 256, 0, stream>>>(up_index, up_orient, down_index, down_orient,
                                                  gcur, binned, NADJ, E, nbkt);
        csr_fill2_kernel<<<nbkt, 256, 0, stream>>>(binned, bstart, end2, packed2, n2);
    } else {
        const int both_blocks = (total + 255) / 256;
        const int nscan = (n2 + SCAN_TILE - 1) / SCAN_TILE;
        hipMemsetAsync(deg2, 0, (size_t)n2 * sizeof(int), stream);
        hist2_kernel<<<both_blocks, 256, 0, stream>>>(up_index + NADJ, down_index + NADJ, deg2, NADJ, E);
        scan_partial<<<nscan, 256, 0, stream>>>(deg2, bsums, n2);
        scan_bsums_k<<<1, 256, 0, stream>>>(bsums, nscan);
        scan_final<<<nscan, 256, 0, stream>>>(deg2, bsums, end2, n2);
        reorder2_kernel<<<both_blocks, 256, 0, stream>>>(up_index, up_orient, down_index, down_orient,
                                                         end2, packed2, NADJ, E);
    }

    // ---- bf16 conversions ----
    conv_bf16_kernel<<<conv_blocks, 256, 0, stream>>>(x, hb, (size_t)E * H64);
    convW_kernel<<<convw_blocks, 256, 0, stream>>>(W_self, W_up, W_down, Wb, L);

    // ---- layers (all state in hb, bf16) ----
    for (int l = 0; l < L; ++l) {
        gather_kernel<<<gather_blocks, 256, 0, stream>>>(
            (const unsigned*)hb, end2, packed2,
            (unsigned*)mupb, (unsigned*)mdnb, E);
        gemm_tanh_mfma<<<gemm_blocks, 256, 0, stream>>>(
            hb, mupb, mdnb, Wb + (size_t)l * 3 * 4096, hb, E, nblk16);
    }

    // ---- readout ----
    hipMemsetAsync(pooled, 0, (size_t)B * H64 * sizeof(float), stream);
    pool_kernel<<<pool_blocks, 256, 0, stream>>>(hb, batch, pooled, E);
    head_kernel<<<B, 64, 0, stream>>>(pooled, lin1_w, lin1_b, lin2_w, lin2_b, out, C);
}